// Round 6
// baseline (479.942 us; speedup 1.0000x reference)
//
#include <hip/hip_runtime.h>
#include <hip/hip_bf16.h>
#include <math.h>

#define BSZ 4
#define NSEQ 2048
#define CDIM 1024
#define NH 16
#define DH 64
#define KC 64
#define KMAX_STRIDE 32   // one kmax slot per 128B cacheline

typedef _Float16 half8_t __attribute__((ext_vector_type(8)));
typedef _Float16 half4_t __attribute__((ext_vector_type(4)));
typedef __fp16 pk2_t __attribute__((ext_vector_type(2)));   // cvt_pkrtz/fdot2 type
typedef __fp16 pk4_t __attribute__((ext_vector_type(4)));
typedef float floatx4 __attribute__((ext_vector_type(4)));

#define GLOBAL_AS(p) ((const __attribute__((address_space(1))) void*)(p))
#define LDS_AS(p)    ((__attribute__((address_space(3))) void*)(p))

// ---------------------------------------------------------------------------
// Prep: fp32 -> fp16 casts (weights transposed to [N][K])
// ---------------------------------------------------------------------------
__global__ __launch_bounds__(256) void cast_x_kernel(
    const float* __restrict__ src, _Float16* __restrict__ dst) {
  const size_t i = ((size_t)blockIdx.x * 256 + threadIdx.x) * 8;
  float4 a = *(const float4*)(src + i);
  float4 b = *(const float4*)(src + i + 4);
  half8_t h;
  h[0] = (_Float16)a.x; h[1] = (_Float16)a.y; h[2] = (_Float16)a.z; h[3] = (_Float16)a.w;
  h[4] = (_Float16)b.x; h[5] = (_Float16)b.y; h[6] = (_Float16)b.z; h[7] = (_Float16)b.w;
  *(half8_t*)(dst + i) = h;
}

__global__ __launch_bounds__(256) void transpose_cast_kernel(
    const float* __restrict__ src, _Float16* __restrict__ dst, int R, int C) {
  __shared__ float Ls[64][65];
  const int t = threadIdx.x;
  const int r0 = blockIdx.y * 64, c0 = blockIdx.x * 64;
  {
    const int lr = t >> 2, lcg = (t & 3) * 16;
    const float* s = src + (size_t)(r0 + lr) * C + c0 + lcg;
#pragma unroll
    for (int u = 0; u < 4; ++u)
      *(float4*)&Ls[lr][lcg + 4 * u] = *(const float4*)(s + 4 * u);
  }
  __syncthreads();
  const int c = t >> 2, rg = (t & 3) * 16;
  half8_t h0, h1;
#pragma unroll
  for (int u = 0; u < 8; ++u) h0[u] = (_Float16)Ls[rg + u][c];
#pragma unroll
  for (int u = 0; u < 8; ++u) h1[u] = (_Float16)Ls[rg + 8 + u][c];
  _Float16* d = dst + (size_t)(c0 + c) * R + r0 + rg;
  *(half8_t*)d = h0;
  *(half8_t*)(d + 8) = h1;
}

// ---------------------------------------------------------------------------
// Kernel 1: QKV GEMM (fp16 MFMA) + bias + RoPE epilogue (unchanged R3).
// ---------------------------------------------------------------------------
__global__ __launch_bounds__(256) void qkv_gemm_kernel(
    const _Float16* __restrict__ xh, const _Float16* __restrict__ Wt,
    const float* __restrict__ bias, _Float16* __restrict__ Qh,
    _Float16* __restrict__ Kh, _Float16* __restrict__ Vh) {
  __shared__ _Float16 As[128 * 64];
  __shared__ _Float16 Bs[128 * 64];
  const int tid = threadIdx.x;
  const int lane = tid & 63, w = tid >> 6;
  const int m = lane & 15, quad = lane >> 4;
  const int wr = (w >> 1) * 64, wc = (w & 1) * 64;
  const int m0 = blockIdx.y * 128;
  const int N0 = blockIdx.x * 128;
  const int sr = lane >> 3, sc = (lane & 7) * 8;

  floatx4 acc[4][4];
#pragma unroll
  for (int i = 0; i < 4; ++i)
#pragma unroll
    for (int j = 0; j < 4; ++j) acc[i][j] = (floatx4){0.f, 0.f, 0.f, 0.f};

  for (int k0 = 0; k0 < CDIM; k0 += 64) {
    __syncthreads();
#pragma unroll
    for (int i = 0; i < 4; ++i) {
      const int row = (w * 4 + i) * 8 + sr;
      __builtin_amdgcn_global_load_lds(
          GLOBAL_AS(xh + (size_t)(m0 + row) * CDIM + k0 + sc),
          LDS_AS(As + (w * 4 + i) * 512), 16, 0, 0);
      __builtin_amdgcn_global_load_lds(
          GLOBAL_AS(Wt + (size_t)(N0 + row) * CDIM + k0 + sc),
          LDS_AS(Bs + (w * 4 + i) * 512), 16, 0, 0);
    }
    __syncthreads();
#pragma unroll
    for (int ks = 0; ks < 2; ++ks) {
      half8_t af[4], bf[4];
#pragma unroll
      for (int mt = 0; mt < 4; ++mt)
        af[mt] = *(half8_t*)(As + (wr + mt * 16 + m) * 64 + ks * 32 + quad * 8);
#pragma unroll
      for (int nt = 0; nt < 4; ++nt)
        bf[nt] = *(half8_t*)(Bs + (wc + nt * 16 + m) * 64 + ks * 32 + quad * 8);
#pragma unroll
      for (int mt = 0; mt < 4; ++mt)
#pragma unroll
        for (int nt = 0; nt < 4; ++nt)
          acc[mt][nt] = __builtin_amdgcn_mfma_f32_16x16x32_f16(
              af[mt], bf[nt], acc[mt][nt], 0, 0, 0);
    }
  }

  const int F0 = N0 + wc;
  const int which = F0 >> 10;
  const int head = (F0 & 1023) >> 6;
  float bv[4];
#pragma unroll
  for (int nt = 0; nt < 4; ++nt) bv[nt] = bias[F0 + nt * 16 + m];

  if (which == 2) {
#pragma unroll
    for (int mt = 0; mt < 4; ++mt)
#pragma unroll
      for (int reg = 0; reg < 4; ++reg) {
        const int gm = m0 + wr + mt * 16 + 4 * quad + reg;
        const int b = gm >> 11, n = gm & 2047;
        const size_t vbase = ((size_t)(b * NH + head) * DH) * NSEQ + n;
#pragma unroll
        for (int nt = 0; nt < 4; ++nt)
          Vh[vbase + (size_t)(nt * 16 + m) * NSEQ] =
              (_Float16)(acc[mt][nt][reg] + bv[nt]);
      }
  } else {
    _Float16* dst = which ? Kh : Qh;
    const float qs = which ? 1.0f : 0.125f * 1.4426950408889634f;
    const float invfA = expf(-9.210340371976184f * ((float)m * (1.0f / 32.0f)));
    const float invfB = expf(-9.210340371976184f * ((float)(16 + m) * (1.0f / 32.0f)));
#pragma unroll
    for (int mt = 0; mt < 4; ++mt)
#pragma unroll
      for (int reg = 0; reg < 4; ++reg) {
        const int gm = m0 + wr + mt * 16 + 4 * quad + reg;
        const int b = gm >> 11, n = gm & 2047;
        float sA, cA, sB, cB;
        sincosf((float)n * invfA, &sA, &cA);
        sincosf((float)n * invfB, &sB, &cB);
        const size_t obase = ((size_t)(b * NH + head) * NSEQ + n) * DH;
#pragma unroll
        for (int nt = 0; nt < 4; ++nt) {
          const float val = acc[mt][nt][reg] + bv[nt];
          const float rot = (nt < 2) ? -(acc[mt][nt + 2][reg] + bv[nt + 2])
                                     :  (acc[mt][nt - 2][reg] + bv[nt - 2]);
          const float sv = (nt & 1) ? sB : sA;
          const float cv = (nt & 1) ? cB : cA;
          dst[obase + nt * 16 + m] = (_Float16)((val * cv + rot * sv) * qs);
        }
      }
  }
}

// ---------------------------------------------------------------------------
// Norm prepass: qn[row] = ||Qh row||; kmax[bh] = max_n ||Kh row||.
// ---------------------------------------------------------------------------
__global__ __launch_bounds__(64) void kmax_init_kernel(unsigned* kmaxu) {
  for (int i = threadIdx.x; i < 64 * KMAX_STRIDE; i += 64) kmaxu[i] = 0u;
}

__global__ __launch_bounds__(256) void qk_norms_kernel(
    const _Float16* __restrict__ Qh, const _Float16* __restrict__ Kh,
    float* __restrict__ qn, unsigned* __restrict__ kmaxu) {
  __shared__ float wmax[4];
  const int tid = threadIdx.x;
  const size_t row = (size_t)blockIdx.x * 32 + (tid >> 3);  // 32 rows, one bh
  const int c = (tid & 7) * 8;
  half8_t q8 = *(const half8_t*)(Qh + row * DH + c);
  half8_t k8 = *(const half8_t*)(Kh + row * DH + c);
  float qs = 0.f, ks = 0.f;
#pragma unroll
  for (int u = 0; u < 8; ++u) {
    const float qv = (float)q8[u], kv = (float)k8[u];
    qs += qv * qv; ks += kv * kv;
  }
  qs += __shfl_xor(qs, 1, 64); ks += __shfl_xor(ks, 1, 64);
  qs += __shfl_xor(qs, 2, 64); ks += __shfl_xor(ks, 2, 64);
  qs += __shfl_xor(qs, 4, 64); ks += __shfl_xor(ks, 4, 64);
  if ((tid & 7) == 0) qn[row] = sqrtf(qs);
  ks = fmaxf(ks, __shfl_xor(ks, 8, 64));
  ks = fmaxf(ks, __shfl_xor(ks, 16, 64));
  ks = fmaxf(ks, __shfl_xor(ks, 32, 64));
  if ((tid & 63) == 0) wmax[tid >> 6] = ks;
  __syncthreads();
  if (tid == 0) {
    const float mx = fmaxf(fmaxf(wmax[0], wmax[1]), fmaxf(wmax[2], wmax[3]));
    atomicMax(&kmaxu[(row >> 11) * KMAX_STRIDE], __float_as_uint(sqrtf(mx)));
  }
}

// ---------------------------------------------------------------------------
// Kernel 2: flash attention, fixed per-row max bound (Cauchy-Schwarz).
// R7: V is NOT staged in LDS — per-bh V (256KB) is L2-resident; PV B-frags
// are 8B-contiguous along the key axis in Vh[d][key], loaded directly to
// registers at chunk start (latency hides under QK^T + exp2). Deletes the
// 16 ds_read_b64 + half the staging per chunk (-50% LDS traffic), halves
// LDS to 18432B (K double-buffer only) -> 8 blocks/CU by LDS. K staging
// stays async reg-staged (T14): issue-early, write-late across the barrier.
// ---------------------------------------------------------------------------
__global__ __launch_bounds__(256) void attn_kernel(
    const _Float16* __restrict__ Qh, const _Float16* __restrict__ Kh,
    const _Float16* __restrict__ Vh, const float* __restrict__ qn,
    const unsigned* __restrict__ kmaxu, _Float16* __restrict__ AO) {
  __shared__ _Float16 smem[9216];   // 2 x Ks[64][72]; epilogue float[64][68]
  float* Os = (float*)smem;

  const int tid = threadIdx.x;
  const int lane = tid & 63;
  const int w = tid >> 6;
  const int m = lane & 15;
  const int quad = lane >> 4;
  const int bh = blockIdx.y;
  const int q0 = blockIdx.x * 128;

  const _Float16* Qb = Qh + (size_t)bh * NSEQ * DH;
  const _Float16* Kb = Kh + (size_t)bh * NSEQ * DH;
  const _Float16* Vb = Vh + (size_t)bh * DH * NSEQ;

  const int rA = q0 + w * 32 + m;
  const int rB = rA + 16;
  half8_t qfA0 = *(const half8_t*)(Qb + (size_t)rA * DH + quad * 8);
  half8_t qfA1 = *(const half8_t*)(Qb + (size_t)rA * DH + 32 + quad * 8);
  half8_t qfB0 = *(const half8_t*)(Qb + (size_t)rB * DH + quad * 8);
  half8_t qfB1 = *(const half8_t*)(Qb + (size_t)rB * DH + 32 + quad * 8);

  const float kmx = __uint_as_float(kmaxu[bh * KMAX_STRIDE]);
  const float mA = qn[(size_t)bh * NSEQ + rA] * kmx;
  const float mB = qn[(size_t)bh * NSEQ + rB] * kmx;

  // K staging: each thread moves 2x half8 per chunk
  const int skey = tid >> 3, sdg = (tid & 7) * 8;
  const _Float16* ksrc0 = Kb + (size_t)skey * DH + sdg;
  const _Float16* ksrc1 = Kb + (size_t)(skey + 32) * DH + sdg;
  const int koff0 = skey * 72 + sdg;
  const int koff1 = (skey + 32) * 72 + sdg;

  // direct-V bases: lane (m,quad) reads V[d = nb*16+m][key = kt*16+quad*4]
  const _Float16* vp0 = Vb + (size_t)(m) * NSEQ + quad * 4;
  const _Float16* vp1 = Vb + (size_t)(16 + m) * NSEQ + quad * 4;
  const _Float16* vp2 = Vb + (size_t)(32 + m) * NSEQ + quad * 4;
  const _Float16* vp3 = Vb + (size_t)(48 + m) * NSEQ + quad * 4;

  half8_t rk0, rk1;  // in-flight K staging registers
  auto LOAD = [&]() {
    rk0 = *(const half8_t*)ksrc0; ksrc0 += KC * DH;
    rk1 = *(const half8_t*)ksrc1; ksrc1 += KC * DH;
  };
  auto WRITE = [&](int boff) {
    _Float16* Ksb = smem + boff;
    *(half8_t*)(Ksb + koff0) = rk0;
    *(half8_t*)(Ksb + koff1) = rk1;
  };

  float lA = 0.f, lB = 0.f;
  floatx4 OA[4], OB[4];
#pragma unroll
  for (int nb = 0; nb < 4; ++nb) {
    OA[nb] = (floatx4){0.f, 0.f, 0.f, 0.f};
    OB[nb] = (floatx4){0.f, 0.f, 0.f, 0.f};
  }
  const pk2_t one2 = {(__fp16)1.f, (__fp16)1.f};

  auto COMPUTE = [&](int boff) {
    _Float16* Ks = smem + boff;
    // issue all V loads for this chunk up front; latency hides under QK^T+exp
    half4_t vf[4][4];
#pragma unroll
    for (int kt = 0; kt < 4; ++kt) {
      vf[kt][0] = *(const half4_t*)(vp0 + kt * 16);
      vf[kt][1] = *(const half4_t*)(vp1 + kt * 16);
      vf[kt][2] = *(const half4_t*)(vp2 + kt * 16);
      vf[kt][3] = *(const half4_t*)(vp3 + kt * 16);
    }
    vp0 += KC; vp1 += KC; vp2 += KC; vp3 += KC;
#pragma unroll
    for (int kt = 0; kt < 4; ++kt) {
      half8_t kf0 = *(half8_t*)(Ks + (kt * 16 + m) * 72 + quad * 8);
      half8_t kf1 = *(half8_t*)(Ks + (kt * 16 + m) * 72 + 32 + quad * 8);
      __builtin_amdgcn_s_setprio(1);
      floatx4 a = (floatx4){-mA, -mA, -mA, -mA};
      a = __builtin_amdgcn_mfma_f32_16x16x32_f16(kf0, qfA0, a, 0, 0, 0);
      a = __builtin_amdgcn_mfma_f32_16x16x32_f16(kf1, qfA1, a, 0, 0, 0);
      floatx4 b = (floatx4){-mB, -mB, -mB, -mB};
      b = __builtin_amdgcn_mfma_f32_16x16x32_f16(kf0, qfB0, b, 0, 0, 0);
      b = __builtin_amdgcn_mfma_f32_16x16x32_f16(kf1, qfB1, b, 0, 0, 0);
      __builtin_amdgcn_s_setprio(0);

      const float pA0 = __builtin_exp2f(a[0]);
      const float pA1 = __builtin_exp2f(a[1]);
      const float pA2 = __builtin_exp2f(a[2]);
      const float pA3 = __builtin_exp2f(a[3]);
      const float pB0 = __builtin_exp2f(b[0]);
      const float pB1 = __builtin_exp2f(b[1]);
      const float pB2 = __builtin_exp2f(b[2]);
      const float pB3 = __builtin_exp2f(b[3]);
      pk2_t a01 = __builtin_amdgcn_cvt_pkrtz(pA0, pA1);
      pk2_t a23 = __builtin_amdgcn_cvt_pkrtz(pA2, pA3);
      pk2_t b01 = __builtin_amdgcn_cvt_pkrtz(pB0, pB1);
      pk2_t b23 = __builtin_amdgcn_cvt_pkrtz(pB2, pB3);
      lA = __builtin_amdgcn_fdot2(a01, one2, lA, false);
      lA = __builtin_amdgcn_fdot2(a23, one2, lA, false);
      lB = __builtin_amdgcn_fdot2(b01, one2, lB, false);
      lB = __builtin_amdgcn_fdot2(b23, one2, lB, false);
      half4_t phA = __builtin_bit_cast(
          half4_t, (pk4_t)__builtin_shufflevector(a01, a23, 0, 1, 2, 3));
      half4_t phB = __builtin_bit_cast(
          half4_t, (pk4_t)__builtin_shufflevector(b01, b23, 0, 1, 2, 3));

      __builtin_amdgcn_s_setprio(1);
#pragma unroll
      for (int nb = 0; nb < 4; ++nb) {
        OA[nb] = __builtin_amdgcn_mfma_f32_16x16x16f16(phA, vf[kt][nb], OA[nb], 0, 0, 0);
        OB[nb] = __builtin_amdgcn_mfma_f32_16x16x16f16(phB, vf[kt][nb], OB[nb], 0, 0, 0);
      }
      __builtin_amdgcn_s_setprio(0);
    }
  };

  // pipeline prologue: chunk0 -> buf0; issue K loads for chunk1
  LOAD();
  WRITE(0);
  LOAD();

  const int NCK = NSEQ / KC;  // 32
  for (int ck = 0; ck < NCK; ++ck) {
    __syncthreads();               // buf[ck&1] writes visible; prev reads done
    COMPUTE((ck & 1) * 4608);
    if (ck + 1 < NCK) {
      WRITE(((ck + 1) & 1) * 4608);  // waits on in-flight loads (vmcnt)
      if (ck + 2 < NCK) LOAD();      // in flight across barrier + next compute
    }
  }

  // row-sum across quads (lanes differing in bits 4,5)
  lA += __shfl_xor(lA, 16, 64); lA += __shfl_xor(lA, 32, 64);
  lB += __shfl_xor(lB, 16, 64); lB += __shfl_xor(lB, 32, 64);
  float lA4[4], lB4[4];
#pragma unroll
  for (int r = 0; r < 4; ++r) {
    lA4[r] = __shfl(lA, 4 * quad + r, 64);
    lB4[r] = __shfl(lB, 4 * quad + r, 64);
  }

  const int b = bh >> 4, h = bh & 15;
  const int ql = tid >> 2, dgo = (tid & 3) * 16;
  const int gq = q0 + (ql >> 4) * 32 + (ql & 15);
  _Float16* dstA = AO + ((size_t)(b * NSEQ + gq)) * CDIM + h * DH + dgo;

  // ---- pass A: rows w*32 + [0,16) of the block's 128 ----
  __syncthreads();
#pragma unroll
  for (int nb = 0; nb < 4; ++nb)
#pragma unroll
    for (int r = 0; r < 4; ++r)
      Os[(w * 16 + 4 * quad + r) * 68 + nb * 16 + m] = OA[nb][r] * (1.0f / lA4[r]);
  __syncthreads();
#pragma unroll
  for (int u = 0; u < 2; ++u) {
    half8_t o;
#pragma unroll
    for (int v = 0; v < 8; ++v) o[v] = (_Float16)Os[ql * 68 + dgo + u * 8 + v];
    *(half8_t*)(dstA + u * 8) = o;
  }

  // ---- pass B: rows w*32 + [16,32) ----
  __syncthreads();
#pragma unroll
  for (int nb = 0; nb < 4; ++nb)
#pragma unroll
    for (int r = 0; r < 4; ++r)
      Os[(w * 16 + 4 * quad + r) * 68 + nb * 16 + m] = OB[nb][r] * (1.0f / lB4[r]);
  __syncthreads();
  _Float16* dstB = dstA + (size_t)16 * CDIM;
#pragma unroll
  for (int u = 0; u < 2; ++u) {
    half8_t o;
#pragma unroll
    for (int v = 0; v < 8; ++v) o[v] = (_Float16)Os[ql * 68 + dgo + u * 8 + v];
    *(half8_t*)(dstB + u * 8) = o;
  }
}

// ---------------------------------------------------------------------------
// Kernel 3: proj GEMM (fp16 MFMA) + bias, fp32 out (unchanged R3).
// ---------------------------------------------------------------------------
__global__ __launch_bounds__(256) void proj_gemm_kernel(
    const _Float16* __restrict__ Ah, const _Float16* __restrict__ Wt,
    const float* __restrict__ bias, float* __restrict__ out) {
  __shared__ _Float16 As[128 * 64];
  __shared__ _Float16 Bs[128 * 64];
  const int tid = threadIdx.x;
  const int lane = tid & 63, w = tid >> 6;
  const int m = lane & 15, quad = lane >> 4;
  const int wr = (w >> 1) * 64, wc = (w & 1) * 64;
  const int m0 = blockIdx.y * 128;
  const int N0 = blockIdx.x * 128;
  const int sr = lane >> 3, sc = (lane & 7) * 8;

  floatx4 acc[4][4];
#pragma unroll
  for (int i = 0; i < 4; ++i)
#pragma unroll
    for (int j = 0; j < 4; ++j) acc[i][j] = (floatx4){0.f, 0.f, 0.f, 0.f};

  for (int k0 = 0; k0 < CDIM; k0 += 64) {
    __syncthreads();
#pragma unroll
    for (int i = 0; i < 4; ++i) {
      const int row = (w * 4 + i) * 8 + sr;
      __builtin_amdgcn_global_load_lds(
          GLOBAL_AS(Ah + (size_t)(m0 + row) * CDIM + k0 + sc),
          LDS_AS(As + (w * 4 + i) * 512), 16, 0, 0);
      __builtin_amdgcn_global_load_lds(
          GLOBAL_AS(Wt + (size_t)(N0 + row) * CDIM + k0 + sc),
          LDS_AS(Bs + (w * 4 + i) * 512), 16, 0, 0);
    }
    __syncthreads();
#pragma unroll
    for (int ks = 0; ks < 2; ++ks) {
      half8_t af[4], bf[4];
#pragma unroll
      for (int mt = 0; mt < 4; ++mt)
        af[mt] = *(half8_t*)(As + (wr + mt * 16 + m) * 64 + ks * 32 + quad * 8);
#pragma unroll
      for (int nt = 0; nt < 4; ++nt)
        bf[nt] = *(half8_t*)(Bs + (wc + nt * 16 + m) * 64 + ks * 32 + quad * 8);
#pragma unroll
      for (int mt = 0; mt < 4; ++mt)
#pragma unroll
        for (int nt = 0; nt < 4; ++nt)
          acc[mt][nt] = __builtin_amdgcn_mfma_f32_16x16x32_f16(
              af[mt], bf[nt], acc[mt][nt], 0, 0, 0);
    }
  }

  const int F0 = N0 + wc;
  float bv[4];
#pragma unroll
  for (int nt = 0; nt < 4; ++nt) bv[nt] = bias[F0 + nt * 16 + m];
#pragma unroll
  for (int mt = 0; mt < 4; ++mt)
#pragma unroll
    for (int reg = 0; reg < 4; ++reg) {
      const int gm = m0 + wr + mt * 16 + 4 * quad + reg;
#pragma unroll
      for (int nt = 0; nt < 4; ++nt)
        out[(size_t)gm * CDIM + F0 + nt * 16 + m] = acc[mt][nt][reg] + bv[nt];
    }
}

// ---------------------------------------------------------------------------
extern "C" void kernel_launch(void* const* d_in, const int* in_sizes, int n_in,
                              void* d_out, int out_size, void* d_ws, size_t ws_size,
                              hipStream_t stream) {
  const float* x     = (const float*)d_in[0];
  const float* Wqkv  = (const float*)d_in[1];
  const float* bqkv  = (const float*)d_in[2];
  const float* Wproj = (const float*)d_in[3];
  const float* bproj = (const float*)d_in[4];
  float* out = (float*)d_out;

  const size_t per = (size_t)BSZ * NH * NSEQ * DH;  // 8,388,608
  _Float16* xh  = (_Float16*)d_ws;
  _Float16* Wt  = xh + per;                 // [3072][1024]
  _Float16* Wpt = Wt + (size_t)3072 * 1024; // [1024][1024]
  _Float16* Qh  = Wpt + (size_t)1024 * 1024;
  _Float16* Kh  = Qh + per;
  _Float16* Vh  = Kh + per;
  _Float16* AOh = Vh + per;
  float*    qnp = (float*)(AOh + per);      // [64*2048] q-row norms
  unsigned* kmx = (unsigned*)(qnp + (size_t)64 * NSEQ);  // [64*KMAX_STRIDE]

  cast_x_kernel<<<4096, 256, 0, stream>>>(x, xh);
  transpose_cast_kernel<<<dim3(48, 16), 256, 0, stream>>>(Wqkv, Wt, 1024, 3072);
  transpose_cast_kernel<<<dim3(16, 16), 256, 0, stream>>>(Wproj, Wpt, 1024, 1024);
  kmax_init_kernel<<<1, 64, 0, stream>>>(kmx);
  qkv_gemm_kernel<<<dim3(24, 64), 256, 0, stream>>>(xh, Wt, bqkv, Qh, Kh, Vh);
  qk_norms_kernel<<<4096, 256, 0, stream>>>(Qh, Kh, qnp, kmx);
  attn_kernel<<<dim3(16, 64), 256, 0, stream>>>(Qh, Kh, Vh, qnp, kmx, AOh);
  proj_gemm_kernel<<<dim3(8, 64), 256, 0, stream>>>(AOh, Wpt, bproj, out);
}

// Round 7
// 346.604 us; speedup vs baseline: 1.3847x; 1.3847x over previous
//
#include <hip/hip_runtime.h>
#include <hip/hip_bf16.h>
#include <math.h>

#define BSZ 4
#define NSEQ 2048
#define CDIM 1024
#define NH 16
#define DH 64
#define KC 64
#define KMAX_STRIDE 32   // one kmax slot per 128B cacheline

typedef _Float16 half8_t __attribute__((ext_vector_type(8)));
typedef _Float16 half4_t __attribute__((ext_vector_type(4)));
typedef __fp16 pk2_t __attribute__((ext_vector_type(2)));   // cvt_pkrtz/fdot2 type
typedef __fp16 pk4_t __attribute__((ext_vector_type(4)));
typedef float floatx4 __attribute__((ext_vector_type(4)));

#define GLOBAL_AS(p) ((const __attribute__((address_space(1))) void*)(p))
#define LDS_AS(p)    ((__attribute__((address_space(3))) void*)(p))

// ---------------------------------------------------------------------------
// Prep: fp32 -> fp16 casts (weights transposed to [N][K])
// ---------------------------------------------------------------------------
__global__ __launch_bounds__(256) void cast_x_kernel(
    const float* __restrict__ src, _Float16* __restrict__ dst) {
  const size_t i = ((size_t)blockIdx.x * 256 + threadIdx.x) * 8;
  float4 a = *(const float4*)(src + i);
  float4 b = *(const float4*)(src + i + 4);
  half8_t h;
  h[0] = (_Float16)a.x; h[1] = (_Float16)a.y; h[2] = (_Float16)a.z; h[3] = (_Float16)a.w;
  h[4] = (_Float16)b.x; h[5] = (_Float16)b.y; h[6] = (_Float16)b.z; h[7] = (_Float16)b.w;
  *(half8_t*)(dst + i) = h;
}

__global__ __launch_bounds__(256) void transpose_cast_kernel(
    const float* __restrict__ src, _Float16* __restrict__ dst, int R, int C) {
  __shared__ float Ls[64][65];
  const int t = threadIdx.x;
  const int r0 = blockIdx.y * 64, c0 = blockIdx.x * 64;
  {
    const int lr = t >> 2, lcg = (t & 3) * 16;
    const float* s = src + (size_t)(r0 + lr) * C + c0 + lcg;
#pragma unroll
    for (int u = 0; u < 4; ++u)
      *(float4*)&Ls[lr][lcg + 4 * u] = *(const float4*)(s + 4 * u);
  }
  __syncthreads();
  const int c = t >> 2, rg = (t & 3) * 16;
  half8_t h0, h1;
#pragma unroll
  for (int u = 0; u < 8; ++u) h0[u] = (_Float16)Ls[rg + u][c];
#pragma unroll
  for (int u = 0; u < 8; ++u) h1[u] = (_Float16)Ls[rg + 8 + u][c];
  _Float16* d = dst + (size_t)(c0 + c) * R + r0 + rg;
  *(half8_t*)d = h0;
  *(half8_t*)(d + 8) = h1;
}

// ---------------------------------------------------------------------------
// Kernel 1: QKV GEMM (fp16 MFMA) + bias + RoPE epilogue (unchanged R3).
// ---------------------------------------------------------------------------
__global__ __launch_bounds__(256) void qkv_gemm_kernel(
    const _Float16* __restrict__ xh, const _Float16* __restrict__ Wt,
    const float* __restrict__ bias, _Float16* __restrict__ Qh,
    _Float16* __restrict__ Kh, _Float16* __restrict__ Vh) {
  __shared__ _Float16 As[128 * 64];
  __shared__ _Float16 Bs[128 * 64];
  const int tid = threadIdx.x;
  const int lane = tid & 63, w = tid >> 6;
  const int m = lane & 15, quad = lane >> 4;
  const int wr = (w >> 1) * 64, wc = (w & 1) * 64;
  const int m0 = blockIdx.y * 128;
  const int N0 = blockIdx.x * 128;
  const int sr = lane >> 3, sc = (lane & 7) * 8;

  floatx4 acc[4][4];
#pragma unroll
  for (int i = 0; i < 4; ++i)
#pragma unroll
    for (int j = 0; j < 4; ++j) acc[i][j] = (floatx4){0.f, 0.f, 0.f, 0.f};

  for (int k0 = 0; k0 < CDIM; k0 += 64) {
    __syncthreads();
#pragma unroll
    for (int i = 0; i < 4; ++i) {
      const int row = (w * 4 + i) * 8 + sr;
      __builtin_amdgcn_global_load_lds(
          GLOBAL_AS(xh + (size_t)(m0 + row) * CDIM + k0 + sc),
          LDS_AS(As + (w * 4 + i) * 512), 16, 0, 0);
      __builtin_amdgcn_global_load_lds(
          GLOBAL_AS(Wt + (size_t)(N0 + row) * CDIM + k0 + sc),
          LDS_AS(Bs + (w * 4 + i) * 512), 16, 0, 0);
    }
    __syncthreads();
#pragma unroll
    for (int ks = 0; ks < 2; ++ks) {
      half8_t af[4], bf[4];
#pragma unroll
      for (int mt = 0; mt < 4; ++mt)
        af[mt] = *(half8_t*)(As + (wr + mt * 16 + m) * 64 + ks * 32 + quad * 8);
#pragma unroll
      for (int nt = 0; nt < 4; ++nt)
        bf[nt] = *(half8_t*)(Bs + (wc + nt * 16 + m) * 64 + ks * 32 + quad * 8);
#pragma unroll
      for (int mt = 0; mt < 4; ++mt)
#pragma unroll
        for (int nt = 0; nt < 4; ++nt)
          acc[mt][nt] = __builtin_amdgcn_mfma_f32_16x16x32_f16(
              af[mt], bf[nt], acc[mt][nt], 0, 0, 0);
    }
  }

  const int F0 = N0 + wc;
  const int which = F0 >> 10;
  const int head = (F0 & 1023) >> 6;
  float bv[4];
#pragma unroll
  for (int nt = 0; nt < 4; ++nt) bv[nt] = bias[F0 + nt * 16 + m];

  if (which == 2) {
#pragma unroll
    for (int mt = 0; mt < 4; ++mt)
#pragma unroll
      for (int reg = 0; reg < 4; ++reg) {
        const int gm = m0 + wr + mt * 16 + 4 * quad + reg;
        const int b = gm >> 11, n = gm & 2047;
        const size_t vbase = ((size_t)(b * NH + head) * DH) * NSEQ + n;
#pragma unroll
        for (int nt = 0; nt < 4; ++nt)
          Vh[vbase + (size_t)(nt * 16 + m) * NSEQ] =
              (_Float16)(acc[mt][nt][reg] + bv[nt]);
      }
  } else {
    _Float16* dst = which ? Kh : Qh;
    const float qs = which ? 1.0f : 0.125f * 1.4426950408889634f;
    const float invfA = expf(-9.210340371976184f * ((float)m * (1.0f / 32.0f)));
    const float invfB = expf(-9.210340371976184f * ((float)(16 + m) * (1.0f / 32.0f)));
#pragma unroll
    for (int mt = 0; mt < 4; ++mt)
#pragma unroll
      for (int reg = 0; reg < 4; ++reg) {
        const int gm = m0 + wr + mt * 16 + 4 * quad + reg;
        const int b = gm >> 11, n = gm & 2047;
        float sA, cA, sB, cB;
        sincosf((float)n * invfA, &sA, &cA);
        sincosf((float)n * invfB, &sB, &cB);
        const size_t obase = ((size_t)(b * NH + head) * NSEQ + n) * DH;
#pragma unroll
        for (int nt = 0; nt < 4; ++nt) {
          const float val = acc[mt][nt][reg] + bv[nt];
          const float rot = (nt < 2) ? -(acc[mt][nt + 2][reg] + bv[nt + 2])
                                     :  (acc[mt][nt - 2][reg] + bv[nt - 2]);
          const float sv = (nt & 1) ? sB : sA;
          const float cv = (nt & 1) ? cB : cA;
          dst[obase + nt * 16 + m] = (_Float16)((val * cv + rot * sv) * qs);
        }
      }
  }
}

// ---------------------------------------------------------------------------
// Norm prepass: qn[row] = ||Qh row||; kmax[bh] = max_n ||Kh row||.
// ---------------------------------------------------------------------------
__global__ __launch_bounds__(64) void kmax_init_kernel(unsigned* kmaxu) {
  for (int i = threadIdx.x; i < 64 * KMAX_STRIDE; i += 64) kmaxu[i] = 0u;
}

__global__ __launch_bounds__(256) void qk_norms_kernel(
    const _Float16* __restrict__ Qh, const _Float16* __restrict__ Kh,
    float* __restrict__ qn, unsigned* __restrict__ kmaxu) {
  __shared__ float wmax[4];
  const int tid = threadIdx.x;
  const size_t row = (size_t)blockIdx.x * 32 + (tid >> 3);  // 32 rows, one bh
  const int c = (tid & 7) * 8;
  half8_t q8 = *(const half8_t*)(Qh + row * DH + c);
  half8_t k8 = *(const half8_t*)(Kh + row * DH + c);
  float qs = 0.f, ks = 0.f;
#pragma unroll
  for (int u = 0; u < 8; ++u) {
    const float qv = (float)q8[u], kv = (float)k8[u];
    qs += qv * qv; ks += kv * kv;
  }
  qs += __shfl_xor(qs, 1, 64); ks += __shfl_xor(ks, 1, 64);
  qs += __shfl_xor(qs, 2, 64); ks += __shfl_xor(ks, 2, 64);
  qs += __shfl_xor(qs, 4, 64); ks += __shfl_xor(ks, 4, 64);
  if ((tid & 7) == 0) qn[row] = sqrtf(qs);
  ks = fmaxf(ks, __shfl_xor(ks, 8, 64));
  ks = fmaxf(ks, __shfl_xor(ks, 16, 64));
  ks = fmaxf(ks, __shfl_xor(ks, 32, 64));
  if ((tid & 63) == 0) wmax[tid >> 6] = ks;
  __syncthreads();
  if (tid == 0) {
    const float mx = fmaxf(fmaxf(wmax[0], wmax[1]), fmaxf(wmax[2], wmax[3]));
    atomicMax(&kmaxu[(row >> 11) * KMAX_STRIDE], __float_as_uint(sqrtf(mx)));
  }
}

// ---------------------------------------------------------------------------
// Kernel 2: flash attention, fixed per-row max bound (Cauchy-Schwarz).
// R8: revert V to LDS (R7's direct-L2 V was transaction-rate bound: 16
// cacheline fragments per 8B/lane load). Keep R6 async double-buffer.
// NEW: 256-row q-tile per block (grid 8x64, 2 blocks/CU) — per chunk the
// compute doubles while staging/ds_read/barrier cost stays constant, halving
// per-work overhead. Each wave owns 64 q-rows (4 groups of 16: A,B,C,D).
// ---------------------------------------------------------------------------
__global__ __launch_bounds__(256) void attn_kernel(
    const _Float16* __restrict__ Qh, const _Float16* __restrict__ Kh,
    const _Float16* __restrict__ Vh, const float* __restrict__ qn,
    const unsigned* __restrict__ kmaxu, _Float16* __restrict__ AO) {
  __shared__ _Float16 smem[18432];   // 2 bufs x (Ks[64][72] + Vt[64][72])
  float* Os = (float*)smem;          // [64][68] epilogue reuse

  const int tid = threadIdx.x;
  const int lane = tid & 63;
  const int w = tid >> 6;
  const int m = lane & 15;
  const int quad = lane >> 4;
  const int bh = blockIdx.y;
  const int q0 = blockIdx.x * 256;

  const _Float16* Qb = Qh + (size_t)bh * NSEQ * DH;
  const _Float16* Kb = Kh + (size_t)bh * NSEQ * DH;
  const _Float16* Vb = Vh + (size_t)bh * DH * NSEQ;

  const int rA = q0 + w * 64 + m;
  const int rB = rA + 16;
  const int rC = rA + 32;
  const int rD = rA + 48;
  half8_t qfA0 = *(const half8_t*)(Qb + (size_t)rA * DH + quad * 8);
  half8_t qfA1 = *(const half8_t*)(Qb + (size_t)rA * DH + 32 + quad * 8);
  half8_t qfB0 = *(const half8_t*)(Qb + (size_t)rB * DH + quad * 8);
  half8_t qfB1 = *(const half8_t*)(Qb + (size_t)rB * DH + 32 + quad * 8);
  half8_t qfC0 = *(const half8_t*)(Qb + (size_t)rC * DH + quad * 8);
  half8_t qfC1 = *(const half8_t*)(Qb + (size_t)rC * DH + 32 + quad * 8);
  half8_t qfD0 = *(const half8_t*)(Qb + (size_t)rD * DH + quad * 8);
  half8_t qfD1 = *(const half8_t*)(Qb + (size_t)rD * DH + 32 + quad * 8);

  const float kmx = __uint_as_float(kmaxu[bh * KMAX_STRIDE]);
  const float mA = qn[(size_t)bh * NSEQ + rA] * kmx;
  const float mB = qn[(size_t)bh * NSEQ + rB] * kmx;
  const float mC = qn[(size_t)bh * NSEQ + rC] * kmx;
  const float mD = qn[(size_t)bh * NSEQ + rD] * kmx;

  // staging: each thread moves 4x half8 per chunk (2 K rows, 2 V rows)
  const int skey = tid >> 3, sdg = (tid & 7) * 8;
  const _Float16* ksrc0 = Kb + (size_t)skey * DH + sdg;
  const _Float16* ksrc1 = Kb + (size_t)(skey + 32) * DH + sdg;
  const _Float16* vsrc0 = Vb + (size_t)skey * NSEQ + sdg;
  const _Float16* vsrc1 = Vb + (size_t)(skey + 32) * NSEQ + sdg;
  const int koff0 = skey * 72 + sdg;
  const int koff1 = (skey + 32) * 72 + sdg;
  // buffer b base = b*9216 elements; Vt half = +4608 elements

  half8_t rk0, rk1, rv0, rv1;  // in-flight staging registers
  auto LOAD = [&]() {
    rk0 = *(const half8_t*)ksrc0; ksrc0 += KC * DH;
    rk1 = *(const half8_t*)ksrc1; ksrc1 += KC * DH;
    rv0 = *(const half8_t*)vsrc0; vsrc0 += KC;
    rv1 = *(const half8_t*)vsrc1; vsrc1 += KC;
  };
  auto WRITE = [&](int boff) {
    _Float16* Ksb = smem + boff;
    _Float16* Vtb = smem + boff + 4608;
    *(half8_t*)(Ksb + koff0) = rk0;
    *(half8_t*)(Ksb + koff1) = rk1;
    *(half8_t*)(Vtb + koff0) = rv0;
    *(half8_t*)(Vtb + koff1) = rv1;
  };

  float lA = 0.f, lB = 0.f, lC = 0.f, lD = 0.f;
  floatx4 OA[4], OB[4], OC[4], OD[4];
#pragma unroll
  for (int nb = 0; nb < 4; ++nb) {
    OA[nb] = (floatx4){0.f, 0.f, 0.f, 0.f};
    OB[nb] = (floatx4){0.f, 0.f, 0.f, 0.f};
    OC[nb] = (floatx4){0.f, 0.f, 0.f, 0.f};
    OD[nb] = (floatx4){0.f, 0.f, 0.f, 0.f};
  }
  const pk2_t one2 = {(__fp16)1.f, (__fp16)1.f};

  auto COMPUTE = [&](int boff) {
    _Float16* Ks = smem + boff;
    _Float16* Vt = smem + boff + 4608;
#pragma unroll
    for (int kt = 0; kt < 4; ++kt) {
      half8_t kf0 = *(half8_t*)(Ks + (kt * 16 + m) * 72 + quad * 8);
      half8_t kf1 = *(half8_t*)(Ks + (kt * 16 + m) * 72 + 32 + quad * 8);
      __builtin_amdgcn_s_setprio(1);
      floatx4 a = (floatx4){-mA, -mA, -mA, -mA};
      a = __builtin_amdgcn_mfma_f32_16x16x32_f16(kf0, qfA0, a, 0, 0, 0);
      a = __builtin_amdgcn_mfma_f32_16x16x32_f16(kf1, qfA1, a, 0, 0, 0);
      floatx4 b = (floatx4){-mB, -mB, -mB, -mB};
      b = __builtin_amdgcn_mfma_f32_16x16x32_f16(kf0, qfB0, b, 0, 0, 0);
      b = __builtin_amdgcn_mfma_f32_16x16x32_f16(kf1, qfB1, b, 0, 0, 0);
      floatx4 c = (floatx4){-mC, -mC, -mC, -mC};
      c = __builtin_amdgcn_mfma_f32_16x16x32_f16(kf0, qfC0, c, 0, 0, 0);
      c = __builtin_amdgcn_mfma_f32_16x16x32_f16(kf1, qfC1, c, 0, 0, 0);
      floatx4 d = (floatx4){-mD, -mD, -mD, -mD};
      d = __builtin_amdgcn_mfma_f32_16x16x32_f16(kf0, qfD0, d, 0, 0, 0);
      d = __builtin_amdgcn_mfma_f32_16x16x32_f16(kf1, qfD1, d, 0, 0, 0);
      __builtin_amdgcn_s_setprio(0);

      pk2_t a01 = __builtin_amdgcn_cvt_pkrtz(__builtin_exp2f(a[0]),
                                             __builtin_exp2f(a[1]));
      pk2_t a23 = __builtin_amdgcn_cvt_pkrtz(__builtin_exp2f(a[2]),
                                             __builtin_exp2f(a[3]));
      pk2_t b01 = __builtin_amdgcn_cvt_pkrtz(__builtin_exp2f(b[0]),
                                             __builtin_exp2f(b[1]));
      pk2_t b23 = __builtin_amdgcn_cvt_pkrtz(__builtin_exp2f(b[2]),
                                             __builtin_exp2f(b[3]));
      pk2_t c01 = __builtin_amdgcn_cvt_pkrtz(__builtin_exp2f(c[0]),
                                             __builtin_exp2f(c[1]));
      pk2_t c23 = __builtin_amdgcn_cvt_pkrtz(__builtin_exp2f(c[2]),
                                             __builtin_exp2f(c[3]));
      pk2_t d01 = __builtin_amdgcn_cvt_pkrtz(__builtin_exp2f(d[0]),
                                             __builtin_exp2f(d[1]));
      pk2_t d23 = __builtin_amdgcn_cvt_pkrtz(__builtin_exp2f(d[2]),
                                             __builtin_exp2f(d[3]));
      lA = __builtin_amdgcn_fdot2(a01, one2, lA, false);
      lA = __builtin_amdgcn_fdot2(a23, one2, lA, false);
      lB = __builtin_amdgcn_fdot2(b01, one2, lB, false);
      lB = __builtin_amdgcn_fdot2(b23, one2, lB, false);
      lC = __builtin_amdgcn_fdot2(c01, one2, lC, false);
      lC = __builtin_amdgcn_fdot2(c23, one2, lC, false);
      lD = __builtin_amdgcn_fdot2(d01, one2, lD, false);
      lD = __builtin_amdgcn_fdot2(d23, one2, lD, false);
      half4_t phA = __builtin_bit_cast(
          half4_t, (pk4_t)__builtin_shufflevector(a01, a23, 0, 1, 2, 3));
      half4_t phB = __builtin_bit_cast(
          half4_t, (pk4_t)__builtin_shufflevector(b01, b23, 0, 1, 2, 3));
      half4_t phC = __builtin_bit_cast(
          half4_t, (pk4_t)__builtin_shufflevector(c01, c23, 0, 1, 2, 3));
      half4_t phD = __builtin_bit_cast(
          half4_t, (pk4_t)__builtin_shufflevector(d01, d23, 0, 1, 2, 3));

      __builtin_amdgcn_s_setprio(1);
#pragma unroll
      for (int nb = 0; nb < 4; ++nb) {
        half4_t vf = *(half4_t*)(Vt + (nb * 16 + m) * 72 + kt * 16 + quad * 4);
        OA[nb] = __builtin_amdgcn_mfma_f32_16x16x16f16(phA, vf, OA[nb], 0, 0, 0);
        OB[nb] = __builtin_amdgcn_mfma_f32_16x16x16f16(phB, vf, OB[nb], 0, 0, 0);
        OC[nb] = __builtin_amdgcn_mfma_f32_16x16x16f16(phC, vf, OC[nb], 0, 0, 0);
        OD[nb] = __builtin_amdgcn_mfma_f32_16x16x16f16(phD, vf, OD[nb], 0, 0, 0);
      }
      __builtin_amdgcn_s_setprio(0);
    }
  };

  // pipeline prologue: chunk0 -> buf0; issue loads for chunk1
  LOAD();
  WRITE(0);
  LOAD();

  const int NCK = NSEQ / KC;  // 32
  for (int ck = 0; ck < NCK; ++ck) {
    __syncthreads();               // buf[ck&1] writes visible; prev reads done
    COMPUTE((ck & 1) * 9216);
    if (ck + 1 < NCK) {
      WRITE(((ck + 1) & 1) * 9216);  // waits on in-flight loads (vmcnt)
      if (ck + 2 < NCK) LOAD();      // in flight across barrier + next compute
    }
  }

  // row-sum across quads (lanes differing in bits 4,5)
  lA += __shfl_xor(lA, 16, 64); lA += __shfl_xor(lA, 32, 64);
  lB += __shfl_xor(lB, 16, 64); lB += __shfl_xor(lB, 32, 64);
  lC += __shfl_xor(lC, 16, 64); lC += __shfl_xor(lC, 32, 64);
  lD += __shfl_xor(lD, 16, 64); lD += __shfl_xor(lD, 32, 64);
  float lA4[4], lB4[4], lC4[4], lD4[4];
#pragma unroll
  for (int r = 0; r < 4; ++r) {
    lA4[r] = __shfl(lA, 4 * quad + r, 64);
    lB4[r] = __shfl(lB, 4 * quad + r, 64);
    lC4[r] = __shfl(lC, 4 * quad + r, 64);
    lD4[r] = __shfl(lD, 4 * quad + r, 64);
  }

  const int b = bh >> 4, h = bh & 15;
  const int ql = tid >> 2, dgo = (tid & 3) * 16;
  const int gq = q0 + (ql >> 4) * 64 + (ql & 15);
  _Float16* dst0 = AO + ((size_t)(b * NSEQ + gq)) * CDIM + h * DH + dgo;

  // 4 passes: wave w's OA/OB/OC/OD cover rows q0 + w*64 + P*16 + [0,16)
#define EPI_PASS(OX, lX4, P)                                                   \
  __syncthreads();                                                             \
  _Pragma("unroll")                                                            \
  for (int nb = 0; nb < 4; ++nb)                                               \
    _Pragma("unroll")                                                          \
    for (int r = 0; r < 4; ++r)                                                \
      Os[(w * 16 + 4 * quad + r) * 68 + nb * 16 + m] = OX[nb][r] * (1.0f / lX4[r]); \
  __syncthreads();                                                             \
  {                                                                            \
    _Float16* dstp = dst0 + (size_t)(P * 16) * CDIM;                           \
    _Pragma("unroll")                                                          \
    for (int u = 0; u < 2; ++u) {                                              \
      half8_t o;                                                               \
      _Pragma("unroll")                                                        \
      for (int v = 0; v < 8; ++v) o[v] = (_Float16)Os[ql * 68 + dgo + u * 8 + v]; \
      *(half8_t*)(dstp + u * 8) = o;                                           \
    }                                                                          \
  }

  EPI_PASS(OA, lA4, 0)
  EPI_PASS(OB, lB4, 1)
  EPI_PASS(OC, lC4, 2)
  EPI_PASS(OD, lD4, 3)
#undef EPI_PASS
}

// ---------------------------------------------------------------------------
// Kernel 3: proj GEMM (fp16 MFMA) + bias, fp32 out (unchanged R3).
// ---------------------------------------------------------------------------
__global__ __launch_bounds__(256) void proj_gemm_kernel(
    const _Float16* __restrict__ Ah, const _Float16* __restrict__ Wt,
    const float* __restrict__ bias, float* __restrict__ out) {
  __shared__ _Float16 As[128 * 64];
  __shared__ _Float16 Bs[128 * 64];
  const int tid = threadIdx.x;
  const int lane = tid & 63, w = tid >> 6;
  const int m = lane & 15, quad = lane >> 4;
  const int wr = (w >> 1) * 64, wc = (w & 1) * 64;
  const int m0 = blockIdx.y * 128;
  const int N0 = blockIdx.x * 128;
  const int sr = lane >> 3, sc = (lane & 7) * 8;

  floatx4 acc[4][4];
#pragma unroll
  for (int i = 0; i < 4; ++i)
#pragma unroll
    for (int j = 0; j < 4; ++j) acc[i][j] = (floatx4){0.f, 0.f, 0.f, 0.f};

  for (int k0 = 0; k0 < CDIM; k0 += 64) {
    __syncthreads();
#pragma unroll
    for (int i = 0; i < 4; ++i) {
      const int row = (w * 4 + i) * 8 + sr;
      __builtin_amdgcn_global_load_lds(
          GLOBAL_AS(Ah + (size_t)(m0 + row) * CDIM + k0 + sc),
          LDS_AS(As + (w * 4 + i) * 512), 16, 0, 0);
      __builtin_amdgcn_global_load_lds(
          GLOBAL_AS(Wt + (size_t)(N0 + row) * CDIM + k0 + sc),
          LDS_AS(Bs + (w * 4 + i) * 512), 16, 0, 0);
    }
    __syncthreads();
#pragma unroll
    for (int ks = 0; ks < 2; ++ks) {
      half8_t af[4], bf[4];
#pragma unroll
      for (int mt = 0; mt < 4; ++mt)
        af[mt] = *(half8_t*)(As + (wr + mt * 16 + m) * 64 + ks * 32 + quad * 8);
#pragma unroll
      for (int nt = 0; nt < 4; ++nt)
        bf[nt] = *(half8_t*)(Bs + (wc + nt * 16 + m) * 64 + ks * 32 + quad * 8);
#pragma unroll
      for (int mt = 0; mt < 4; ++mt)
#pragma unroll
        for (int nt = 0; nt < 4; ++nt)
          acc[mt][nt] = __builtin_amdgcn_mfma_f32_16x16x32_f16(
              af[mt], bf[nt], acc[mt][nt], 0, 0, 0);
    }
  }

  const int F0 = N0 + wc;
  float bv[4];
#pragma unroll
  for (int nt = 0; nt < 4; ++nt) bv[nt] = bias[F0 + nt * 16 + m];
#pragma unroll
  for (int mt = 0; mt < 4; ++mt)
#pragma unroll
    for (int reg = 0; reg < 4; ++reg) {
      const int gm = m0 + wr + mt * 16 + 4 * quad + reg;
#pragma unroll
      for (int nt = 0; nt < 4; ++nt)
        out[(size_t)gm * CDIM + F0 + nt * 16 + m] = acc[mt][nt][reg] + bv[nt];
    }
}

// ---------------------------------------------------------------------------
extern "C" void kernel_launch(void* const* d_in, const int* in_sizes, int n_in,
                              void* d_out, int out_size, void* d_ws, size_t ws_size,
                              hipStream_t stream) {
  const float* x     = (const float*)d_in[0];
  const float* Wqkv  = (const float*)d_in[1];
  const float* bqkv  = (const float*)d_in[2];
  const float* Wproj = (const float*)d_in[3];
  const float* bproj = (const float*)d_in[4];
  float* out = (float*)d_out;

  const size_t per = (size_t)BSZ * NH * NSEQ * DH;  // 8,388,608
  _Float16* xh  = (_Float16*)d_ws;
  _Float16* Wt  = xh + per;                 // [3072][1024]
  _Float16* Wpt = Wt + (size_t)3072 * 1024; // [1024][1024]
  _Float16* Qh  = Wpt + (size_t)1024 * 1024;
  _Float16* Kh  = Qh + per;
  _Float16* Vh  = Kh + per;
  _Float16* AOh = Vh + per;
  float*    qnp = (float*)(AOh + per);      // [64*2048] q-row norms
  unsigned* kmx = (unsigned*)(qnp + (size_t)64 * NSEQ);  // [64*KMAX_STRIDE]

  cast_x_kernel<<<4096, 256, 0, stream>>>(x, xh);
  transpose_cast_kernel<<<dim3(48, 16), 256, 0, stream>>>(Wqkv, Wt, 1024, 3072);
  transpose_cast_kernel<<<dim3(16, 16), 256, 0, stream>>>(Wproj, Wpt, 1024, 1024);
  kmax_init_kernel<<<1, 64, 0, stream>>>(kmx);
  qkv_gemm_kernel<<<dim3(24, 64), 256, 0, stream>>>(xh, Wt, bqkv, Qh, Kh, Vh);
  qk_norms_kernel<<<4096, 256, 0, stream>>>(Qh, Kh, qnp, kmx);
  attn_kernel<<<dim3(8, 64), 256, 0, stream>>>(Qh, Kh, Vh, qnp, kmx, AOh);
  proj_gemm_kernel<<<dim3(8, 64), 256, 0, stream>>>(AOh, Wpt, bproj, out);
}

// Round 9
// 333.366 us; speedup vs baseline: 1.4397x; 1.0397x over previous
//
#include <hip/hip_runtime.h>
#include <hip/hip_bf16.h>
#include <math.h>

#define BSZ 4
#define NSEQ 2048
#define CDIM 1024
#define NH 16
#define DH 64
#define KC 64
#define KMAX_STRIDE 32   // one kmax slot per 128B cacheline

typedef _Float16 half8_t __attribute__((ext_vector_type(8)));
typedef _Float16 half4_t __attribute__((ext_vector_type(4)));
typedef __fp16 pk2_t __attribute__((ext_vector_type(2)));   // cvt_pkrtz/fdot2 type
typedef __fp16 pk4_t __attribute__((ext_vector_type(4)));
typedef float floatx4 __attribute__((ext_vector_type(4)));

#define GLOBAL_AS(p) ((const __attribute__((address_space(1))) void*)(p))
#define LDS_AS(p)    ((__attribute__((address_space(3))) void*)(p))

// ---------------------------------------------------------------------------
// Prep: fp32 -> fp16 casts (weights transposed to [N][K])
// ---------------------------------------------------------------------------
__global__ __launch_bounds__(256) void cast_x_kernel(
    const float* __restrict__ src, _Float16* __restrict__ dst) {
  const size_t i = ((size_t)blockIdx.x * 256 + threadIdx.x) * 8;
  float4 a = *(const float4*)(src + i);
  float4 b = *(const float4*)(src + i + 4);
  half8_t h;
  h[0] = (_Float16)a.x; h[1] = (_Float16)a.y; h[2] = (_Float16)a.z; h[3] = (_Float16)a.w;
  h[4] = (_Float16)b.x; h[5] = (_Float16)b.y; h[6] = (_Float16)b.z; h[7] = (_Float16)b.w;
  *(half8_t*)(dst + i) = h;
}

__global__ __launch_bounds__(256) void transpose_cast_kernel(
    const float* __restrict__ src, _Float16* __restrict__ dst, int R, int C) {
  __shared__ float Ls[64][65];
  const int t = threadIdx.x;
  const int r0 = blockIdx.y * 64, c0 = blockIdx.x * 64;
  {
    const int lr = t >> 2, lcg = (t & 3) * 16;
    const float* s = src + (size_t)(r0 + lr) * C + c0 + lcg;
#pragma unroll
    for (int u = 0; u < 4; ++u)
      *(float4*)&Ls[lr][lcg + 4 * u] = *(const float4*)(s + 4 * u);
  }
  __syncthreads();
  const int c = t >> 2, rg = (t & 3) * 16;
  half8_t h0, h1;
#pragma unroll
  for (int u = 0; u < 8; ++u) h0[u] = (_Float16)Ls[rg + u][c];
#pragma unroll
  for (int u = 0; u < 8; ++u) h1[u] = (_Float16)Ls[rg + 8 + u][c];
  _Float16* d = dst + (size_t)(c0 + c) * R + r0 + rg;
  *(half8_t*)d = h0;
  *(half8_t*)(d + 8) = h1;
}

// ---------------------------------------------------------------------------
// RoPE table prep (replaces per-thread sincosf in the qkv epilogue) + kmax
// init folded in. tbl[n*32+f] = (cos, sin) of n * 10000^(-f/32).
// ---------------------------------------------------------------------------
__global__ __launch_bounds__(256) void rope_prep_kernel(
    float2* __restrict__ tbl, unsigned* __restrict__ kmaxu) {
  const int idx = blockIdx.x * 256 + threadIdx.x;   // 65536 entries
  const int n = idx >> 5, f = idx & 31;
  const float invf = expf(-9.210340371976184f * ((float)f * (1.0f / 32.0f)));
  float s, c;
  sincosf((float)n * invf, &s, &c);
  tbl[idx] = make_float2(c, s);
  if (blockIdx.x == 0)
    for (int i = threadIdx.x; i < 64 * KMAX_STRIDE; i += 256) kmaxu[i] = 0u;
}

// ---------------------------------------------------------------------------
// Kernel 1: QKV GEMM (fp16 MFMA) + bias + RoPE epilogue (table-based).
// ---------------------------------------------------------------------------
__global__ __launch_bounds__(256) void qkv_gemm_kernel(
    const _Float16* __restrict__ xh, const _Float16* __restrict__ Wt,
    const float* __restrict__ bias, const float2* __restrict__ rope,
    _Float16* __restrict__ Qh, _Float16* __restrict__ Kh,
    _Float16* __restrict__ Vh) {
  __shared__ _Float16 As[128 * 64];
  __shared__ _Float16 Bs[128 * 64];
  const int tid = threadIdx.x;
  const int lane = tid & 63, w = tid >> 6;
  const int m = lane & 15, quad = lane >> 4;
  const int wr = (w >> 1) * 64, wc = (w & 1) * 64;
  const int m0 = blockIdx.y * 128;
  const int N0 = blockIdx.x * 128;
  const int sr = lane >> 3, sc = (lane & 7) * 8;

  floatx4 acc[4][4];
#pragma unroll
  for (int i = 0; i < 4; ++i)
#pragma unroll
    for (int j = 0; j < 4; ++j) acc[i][j] = (floatx4){0.f, 0.f, 0.f, 0.f};

  for (int k0 = 0; k0 < CDIM; k0 += 64) {
    __syncthreads();
#pragma unroll
    for (int i = 0; i < 4; ++i) {
      const int row = (w * 4 + i) * 8 + sr;
      __builtin_amdgcn_global_load_lds(
          GLOBAL_AS(xh + (size_t)(m0 + row) * CDIM + k0 + sc),
          LDS_AS(As + (w * 4 + i) * 512), 16, 0, 0);
      __builtin_amdgcn_global_load_lds(
          GLOBAL_AS(Wt + (size_t)(N0 + row) * CDIM + k0 + sc),
          LDS_AS(Bs + (w * 4 + i) * 512), 16, 0, 0);
    }
    __syncthreads();
#pragma unroll
    for (int ks = 0; ks < 2; ++ks) {
      half8_t af[4], bf[4];
#pragma unroll
      for (int mt = 0; mt < 4; ++mt)
        af[mt] = *(half8_t*)(As + (wr + mt * 16 + m) * 64 + ks * 32 + quad * 8);
#pragma unroll
      for (int nt = 0; nt < 4; ++nt)
        bf[nt] = *(half8_t*)(Bs + (wc + nt * 16 + m) * 64 + ks * 32 + quad * 8);
#pragma unroll
      for (int mt = 0; mt < 4; ++mt)
#pragma unroll
        for (int nt = 0; nt < 4; ++nt)
          acc[mt][nt] = __builtin_amdgcn_mfma_f32_16x16x32_f16(
              af[mt], bf[nt], acc[mt][nt], 0, 0, 0);
    }
  }

  const int F0 = N0 + wc;
  const int which = F0 >> 10;
  const int head = (F0 & 1023) >> 6;
  float bv[4];
#pragma unroll
  for (int nt = 0; nt < 4; ++nt) bv[nt] = bias[F0 + nt * 16 + m];

  if (which == 2) {
#pragma unroll
    for (int mt = 0; mt < 4; ++mt)
#pragma unroll
      for (int reg = 0; reg < 4; ++reg) {
        const int gm = m0 + wr + mt * 16 + 4 * quad + reg;
        const int b = gm >> 11, n = gm & 2047;
        const size_t vbase = ((size_t)(b * NH + head) * DH) * NSEQ + n;
#pragma unroll
        for (int nt = 0; nt < 4; ++nt)
          Vh[vbase + (size_t)(nt * 16 + m) * NSEQ] =
              (_Float16)(acc[mt][nt][reg] + bv[nt]);
      }
  } else {
    _Float16* dst = which ? Kh : Qh;
    const float qs = which ? 1.0f : 0.125f * 1.4426950408889634f;
#pragma unroll
    for (int mt = 0; mt < 4; ++mt)
#pragma unroll
      for (int reg = 0; reg < 4; ++reg) {
        const int gm = m0 + wr + mt * 16 + 4 * quad + reg;
        const int b = gm >> 11, n = gm & 2047;
        const float2 csA = rope[n * 32 + m];       // freq index m
        const float2 csB = rope[n * 32 + 16 + m];  // freq index 16+m
        const size_t obase = ((size_t)(b * NH + head) * NSEQ + n) * DH;
#pragma unroll
        for (int nt = 0; nt < 4; ++nt) {
          const float val = acc[mt][nt][reg] + bv[nt];
          const float rot = (nt < 2) ? -(acc[mt][nt + 2][reg] + bv[nt + 2])
                                     :  (acc[mt][nt - 2][reg] + bv[nt - 2]);
          const float sv = (nt & 1) ? csB.y : csA.y;
          const float cv = (nt & 1) ? csB.x : csA.x;
          dst[obase + nt * 16 + m] = (_Float16)((val * cv + rot * sv) * qs);
        }
      }
  }
}

// ---------------------------------------------------------------------------
// Norm prepass: qn[row] = ||Qh row||; kmax[bh] = max_n ||Kh row||.
// ---------------------------------------------------------------------------
__global__ __launch_bounds__(256) void qk_norms_kernel(
    const _Float16* __restrict__ Qh, const _Float16* __restrict__ Kh,
    float* __restrict__ qn, unsigned* __restrict__ kmaxu) {
  __shared__ float wmax[4];
  const int tid = threadIdx.x;
  const size_t row = (size_t)blockIdx.x * 32 + (tid >> 3);  // 32 rows, one bh
  const int c = (tid & 7) * 8;
  half8_t q8 = *(const half8_t*)(Qh + row * DH + c);
  half8_t k8 = *(const half8_t*)(Kh + row * DH + c);
  float qs = 0.f, ks = 0.f;
#pragma unroll
  for (int u = 0; u < 8; ++u) {
    const float qv = (float)q8[u], kv = (float)k8[u];
    qs += qv * qv; ks += kv * kv;
  }
  qs += __shfl_xor(qs, 1, 64); ks += __shfl_xor(ks, 1, 64);
  qs += __shfl_xor(qs, 2, 64); ks += __shfl_xor(ks, 2, 64);
  qs += __shfl_xor(qs, 4, 64); ks += __shfl_xor(ks, 4, 64);
  if ((tid & 7) == 0) qn[row] = sqrtf(qs);
  ks = fmaxf(ks, __shfl_xor(ks, 8, 64));
  ks = fmaxf(ks, __shfl_xor(ks, 16, 64));
  ks = fmaxf(ks, __shfl_xor(ks, 32, 64));
  if ((tid & 63) == 0) wmax[tid >> 6] = ks;
  __syncthreads();
  if (tid == 0) {
    const float mx = fmaxf(fmaxf(wmax[0], wmax[1]), fmaxf(wmax[2], wmax[3]));
    atomicMax(&kmaxu[(row >> 11) * KMAX_STRIDE], __float_as_uint(sqrtf(mx)));
  }
}

// ---------------------------------------------------------------------------
// Kernel 2: flash attention (R6 structure = best measured: async dbuf,
// 128-row q-tile, 4 waves). NEW (T1): 1-D grid with XCD-aware decode —
// id%8 selects XCD (dispatch round-robin); bh%8 pinned to it so all 16
// q-blocks of one bh share an XCD's L2 (K/V fetched once per XCD, not 8x).
// Blocks of one bh are also temporally clustered (consecutive ids, stride 8).
// ---------------------------------------------------------------------------
__global__ __launch_bounds__(256) void attn_kernel(
    const _Float16* __restrict__ Qh, const _Float16* __restrict__ Kh,
    const _Float16* __restrict__ Vh, const float* __restrict__ qn,
    const unsigned* __restrict__ kmaxu, _Float16* __restrict__ AO) {
  __shared__ _Float16 smem[18432];   // 2 bufs x (Ks[64][72] + Vt[64][72])
  float* Os = (float*)smem;          // [64][68] epilogue reuse

  const int tid = threadIdx.x;
  const int lane = tid & 63;
  const int w = tid >> 6;
  const int m = lane & 15;
  const int quad = lane >> 4;

  // XCD-aware decode: slot = id%8 (XCD), k = id/8; bh = slot + 8*(k/16)
  const int bid = blockIdx.x;
  const int slot = bid & 7, kk = bid >> 3;
  const int bh = slot + 8 * (kk >> 4);
  const int q0 = (kk & 15) * 128;

  const _Float16* Qb = Qh + (size_t)bh * NSEQ * DH;
  const _Float16* Kb = Kh + (size_t)bh * NSEQ * DH;
  const _Float16* Vb = Vh + (size_t)bh * DH * NSEQ;

  const int rA = q0 + w * 32 + m;
  const int rB = rA + 16;
  half8_t qfA0 = *(const half8_t*)(Qb + (size_t)rA * DH + quad * 8);
  half8_t qfA1 = *(const half8_t*)(Qb + (size_t)rA * DH + 32 + quad * 8);
  half8_t qfB0 = *(const half8_t*)(Qb + (size_t)rB * DH + quad * 8);
  half8_t qfB1 = *(const half8_t*)(Qb + (size_t)rB * DH + 32 + quad * 8);

  const float kmx = __uint_as_float(kmaxu[bh * KMAX_STRIDE]);
  const float mA = qn[(size_t)bh * NSEQ + rA] * kmx;
  const float mB = qn[(size_t)bh * NSEQ + rB] * kmx;

  // staging: each thread moves 4x half8 per chunk (2 K rows, 2 V rows)
  const int skey = tid >> 3, sdg = (tid & 7) * 8;
  const _Float16* ksrc0 = Kb + (size_t)skey * DH + sdg;
  const _Float16* ksrc1 = Kb + (size_t)(skey + 32) * DH + sdg;
  const _Float16* vsrc0 = Vb + (size_t)skey * NSEQ + sdg;
  const _Float16* vsrc1 = Vb + (size_t)(skey + 32) * NSEQ + sdg;
  const int koff0 = skey * 72 + sdg;
  const int koff1 = (skey + 32) * 72 + sdg;
  // buffer b base = b*9216 elements; Vt half = +4608 elements

  half8_t rk0, rk1, rv0, rv1;  // in-flight staging registers
  auto LOAD = [&]() {
    rk0 = *(const half8_t*)ksrc0; ksrc0 += KC * DH;
    rk1 = *(const half8_t*)ksrc1; ksrc1 += KC * DH;
    rv0 = *(const half8_t*)vsrc0; vsrc0 += KC;
    rv1 = *(const half8_t*)vsrc1; vsrc1 += KC;
  };
  auto WRITE = [&](int boff) {
    _Float16* Ksb = smem + boff;
    _Float16* Vtb = smem + boff + 4608;
    *(half8_t*)(Ksb + koff0) = rk0;
    *(half8_t*)(Ksb + koff1) = rk1;
    *(half8_t*)(Vtb + koff0) = rv0;
    *(half8_t*)(Vtb + koff1) = rv1;
  };

  float lA = 0.f, lB = 0.f;
  floatx4 OA[4], OB[4];
#pragma unroll
  for (int nb = 0; nb < 4; ++nb) {
    OA[nb] = (floatx4){0.f, 0.f, 0.f, 0.f};
    OB[nb] = (floatx4){0.f, 0.f, 0.f, 0.f};
  }
  const pk2_t one2 = {(__fp16)1.f, (__fp16)1.f};

  auto COMPUTE = [&](int boff) {
    _Float16* Ks = smem + boff;
    _Float16* Vt = smem + boff + 4608;
#pragma unroll
    for (int kt = 0; kt < 4; ++kt) {
      half8_t kf0 = *(half8_t*)(Ks + (kt * 16 + m) * 72 + quad * 8);
      half8_t kf1 = *(half8_t*)(Ks + (kt * 16 + m) * 72 + 32 + quad * 8);
      __builtin_amdgcn_s_setprio(1);
      floatx4 a = (floatx4){-mA, -mA, -mA, -mA};
      a = __builtin_amdgcn_mfma_f32_16x16x32_f16(kf0, qfA0, a, 0, 0, 0);
      a = __builtin_amdgcn_mfma_f32_16x16x32_f16(kf1, qfA1, a, 0, 0, 0);
      floatx4 b = (floatx4){-mB, -mB, -mB, -mB};
      b = __builtin_amdgcn_mfma_f32_16x16x32_f16(kf0, qfB0, b, 0, 0, 0);
      b = __builtin_amdgcn_mfma_f32_16x16x32_f16(kf1, qfB1, b, 0, 0, 0);
      __builtin_amdgcn_s_setprio(0);

      const float pA0 = __builtin_exp2f(a[0]);
      const float pA1 = __builtin_exp2f(a[1]);
      const float pA2 = __builtin_exp2f(a[2]);
      const float pA3 = __builtin_exp2f(a[3]);
      const float pB0 = __builtin_exp2f(b[0]);
      const float pB1 = __builtin_exp2f(b[1]);
      const float pB2 = __builtin_exp2f(b[2]);
      const float pB3 = __builtin_exp2f(b[3]);
      pk2_t a01 = __builtin_amdgcn_cvt_pkrtz(pA0, pA1);
      pk2_t a23 = __builtin_amdgcn_cvt_pkrtz(pA2, pA3);
      pk2_t b01 = __builtin_amdgcn_cvt_pkrtz(pB0, pB1);
      pk2_t b23 = __builtin_amdgcn_cvt_pkrtz(pB2, pB3);
      lA = __builtin_amdgcn_fdot2(a01, one2, lA, false);
      lA = __builtin_amdgcn_fdot2(a23, one2, lA, false);
      lB = __builtin_amdgcn_fdot2(b01, one2, lB, false);
      lB = __builtin_amdgcn_fdot2(b23, one2, lB, false);
      half4_t phA = __builtin_bit_cast(
          half4_t, (pk4_t)__builtin_shufflevector(a01, a23, 0, 1, 2, 3));
      half4_t phB = __builtin_bit_cast(
          half4_t, (pk4_t)__builtin_shufflevector(b01, b23, 0, 1, 2, 3));

      __builtin_amdgcn_s_setprio(1);
#pragma unroll
      for (int nb = 0; nb < 4; ++nb) {
        half4_t vf = *(half4_t*)(Vt + (nb * 16 + m) * 72 + kt * 16 + quad * 4);
        OA[nb] = __builtin_amdgcn_mfma_f32_16x16x16f16(phA, vf, OA[nb], 0, 0, 0);
        OB[nb] = __builtin_amdgcn_mfma_f32_16x16x16f16(phB, vf, OB[nb], 0, 0, 0);
      }
      __builtin_amdgcn_s_setprio(0);
    }
  };

  // pipeline prologue: chunk0 -> buf0; issue loads for chunk1
  LOAD();
  WRITE(0);
  LOAD();

  const int NCK = NSEQ / KC;  // 32
  for (int ck = 0; ck < NCK; ++ck) {
    __syncthreads();               // buf[ck&1] writes visible; prev reads done
    COMPUTE((ck & 1) * 9216);
    if (ck + 1 < NCK) {
      WRITE(((ck + 1) & 1) * 9216);  // waits on in-flight loads (vmcnt)
      if (ck + 2 < NCK) LOAD();      // in flight across barrier + next compute
    }
  }

  // row-sum across quads (lanes differing in bits 4,5)
  lA += __shfl_xor(lA, 16, 64); lA += __shfl_xor(lA, 32, 64);
  lB += __shfl_xor(lB, 16, 64); lB += __shfl_xor(lB, 32, 64);
  float lA4[4], lB4[4];
#pragma unroll
  for (int r = 0; r < 4; ++r) {
    lA4[r] = __shfl(lA, 4 * quad + r, 64);
    lB4[r] = __shfl(lB, 4 * quad + r, 64);
  }

  const int b = bh >> 4, h = bh & 15;
  const int ql = tid >> 2, dgo = (tid & 3) * 16;
  const int gq = q0 + (ql >> 4) * 32 + (ql & 15);
  _Float16* dstA = AO + ((size_t)(b * NSEQ + gq)) * CDIM + h * DH + dgo;

  // ---- pass A: rows w*32 + [0,16) of the block's 128 ----
  __syncthreads();
#pragma unroll
  for (int nb = 0; nb < 4; ++nb)
#pragma unroll
    for (int r = 0; r < 4; ++r)
      Os[(w * 16 + 4 * quad + r) * 68 + nb * 16 + m] = OA[nb][r] * (1.0f / lA4[r]);
  __syncthreads();
#pragma unroll
  for (int u = 0; u < 2; ++u) {
    half8_t o;
#pragma unroll
    for (int v = 0; v < 8; ++v) o[v] = (_Float16)Os[ql * 68 + dgo + u * 8 + v];
    *(half8_t*)(dstA + u * 8) = o;
  }

  // ---- pass B: rows w*32 + [16,32) ----
  __syncthreads();
#pragma unroll
  for (int nb = 0; nb < 4; ++nb)
#pragma unroll
    for (int r = 0; r < 4; ++r)
      Os[(w * 16 + 4 * quad + r) * 68 + nb * 16 + m] = OB[nb][r] * (1.0f / lB4[r]);
  __syncthreads();
  _Float16* dstB = dstA + (size_t)16 * CDIM;
#pragma unroll
  for (int u = 0; u < 2; ++u) {
    half8_t o;
#pragma unroll
    for (int v = 0; v < 8; ++v) o[v] = (_Float16)Os[ql * 68 + dgo + u * 8 + v];
    *(half8_t*)(dstB + u * 8) = o;
  }
}

// ---------------------------------------------------------------------------
// Kernel 3: proj GEMM (fp16 MFMA) + bias, fp32 out (unchanged R3).
// ---------------------------------------------------------------------------
__global__ __launch_bounds__(256) void proj_gemm_kernel(
    const _Float16* __restrict__ Ah, const _Float16* __restrict__ Wt,
    const float* __restrict__ bias, float* __restrict__ out) {
  __shared__ _Float16 As[128 * 64];
  __shared__ _Float16 Bs[128 * 64];
  const int tid = threadIdx.x;
  const int lane = tid & 63, w = tid >> 6;
  const int m = lane & 15, quad = lane >> 4;
  const int wr = (w >> 1) * 64, wc = (w & 1) * 64;
  const int m0 = blockIdx.y * 128;
  const int N0 = blockIdx.x * 128;
  const int sr = lane >> 3, sc = (lane & 7) * 8;

  floatx4 acc[4][4];
#pragma unroll
  for (int i = 0; i < 4; ++i)
#pragma unroll
    for (int j = 0; j < 4; ++j) acc[i][j] = (floatx4){0.f, 0.f, 0.f, 0.f};

  for (int k0 = 0; k0 < CDIM; k0 += 64) {
    __syncthreads();
#pragma unroll
    for (int i = 0; i < 4; ++i) {
      const int row = (w * 4 + i) * 8 + sr;
      __builtin_amdgcn_global_load_lds(
          GLOBAL_AS(Ah + (size_t)(m0 + row) * CDIM + k0 + sc),
          LDS_AS(As + (w * 4 + i) * 512), 16, 0, 0);
      __builtin_amdgcn_global_load_lds(
          GLOBAL_AS(Wt + (size_t)(N0 + row) * CDIM + k0 + sc),
          LDS_AS(Bs + (w * 4 + i) * 512), 16, 0, 0);
    }
    __syncthreads();
#pragma unroll
    for (int ks = 0; ks < 2; ++ks) {
      half8_t af[4], bf[4];
#pragma unroll
      for (int mt = 0; mt < 4; ++mt)
        af[mt] = *(half8_t*)(As + (wr + mt * 16 + m) * 64 + ks * 32 + quad * 8);
#pragma unroll
      for (int nt = 0; nt < 4; ++nt)
        bf[nt] = *(half8_t*)(Bs + (wc + nt * 16 + m) * 64 + ks * 32 + quad * 8);
#pragma unroll
      for (int mt = 0; mt < 4; ++mt)
#pragma unroll
        for (int nt = 0; nt < 4; ++nt)
          acc[mt][nt] = __builtin_amdgcn_mfma_f32_16x16x32_f16(
              af[mt], bf[nt], acc[mt][nt], 0, 0, 0);
    }
  }

  const int F0 = N0 + wc;
  float bv[4];
#pragma unroll
  for (int nt = 0; nt < 4; ++nt) bv[nt] = bias[F0 + nt * 16 + m];
#pragma unroll
  for (int mt = 0; mt < 4; ++mt)
#pragma unroll
    for (int reg = 0; reg < 4; ++reg) {
      const int gm = m0 + wr + mt * 16 + 4 * quad + reg;
#pragma unroll
      for (int nt = 0; nt < 4; ++nt)
        out[(size_t)gm * CDIM + F0 + nt * 16 + m] = acc[mt][nt][reg] + bv[nt];
    }
}

// ---------------------------------------------------------------------------
extern "C" void kernel_launch(void* const* d_in, const int* in_sizes, int n_in,
                              void* d_out, int out_size, void* d_ws, size_t ws_size,
                              hipStream_t stream) {
  const float* x     = (const float*)d_in[0];
  const float* Wqkv  = (const float*)d_in[1];
  const float* bqkv  = (const float*)d_in[2];
  const float* Wproj = (const float*)d_in[3];
  const float* bproj = (const float*)d_in[4];
  float* out = (float*)d_out;

  const size_t per = (size_t)BSZ * NH * NSEQ * DH;  // 8,388,608
  _Float16* xh  = (_Float16*)d_ws;
  _Float16* Wt  = xh + per;                 // [3072][1024]
  _Float16* Wpt = Wt + (size_t)3072 * 1024; // [1024][1024]
  _Float16* Qh  = Wpt + (size_t)1024 * 1024;
  _Float16* Kh  = Qh + per;
  _Float16* Vh  = Kh + per;
  _Float16* AOh = Vh + per;
  float*    qnp = (float*)(AOh + per);      // [64*2048] q-row norms
  unsigned* kmx = (unsigned*)(qnp + (size_t)64 * NSEQ);  // [64*KMAX_STRIDE]
  float2*   ropet = (float2*)(kmx + 64 * KMAX_STRIDE);   // [2048*32] (cos,sin)

  cast_x_kernel<<<4096, 256, 0, stream>>>(x, xh);
  transpose_cast_kernel<<<dim3(48, 16), 256, 0, stream>>>(Wqkv, Wt, 1024, 3072);
  transpose_cast_kernel<<<dim3(16, 16), 256, 0, stream>>>(Wproj, Wpt, 1024, 1024);
  rope_prep_kernel<<<256, 256, 0, stream>>>(ropet, kmx);
  qkv_gemm_kernel<<<dim3(24, 64), 256, 0, stream>>>(xh, Wt, bqkv, ropet, Qh, Kh, Vh);
  qk_norms_kernel<<<4096, 256, 0, stream>>>(Qh, Kh, qnp, kmx);
  attn_kernel<<<1024, 256, 0, stream>>>(Qh, Kh, Vh, qnp, kmx, AOh);
  proj_gemm_kernel<<<dim3(8, 64), 256, 0, stream>>>(AOh, Wpt, bproj, out);
}

// Round 10
// 319.271 us; speedup vs baseline: 1.5032x; 1.0441x over previous
//
#include <hip/hip_runtime.h>
#include <hip/hip_bf16.h>
#include <math.h>

#define BSZ 4
#define NSEQ 2048
#define CDIM 1024
#define NH 16
#define DH 64
#define KC 64
#define KMAX_STRIDE 32   // one kmax slot per 128B cacheline

typedef _Float16 half8_t __attribute__((ext_vector_type(8)));
typedef _Float16 half4_t __attribute__((ext_vector_type(4)));
typedef __fp16 pk2_t __attribute__((ext_vector_type(2)));   // cvt_pkrtz/fdot2 type
typedef __fp16 pk4_t __attribute__((ext_vector_type(4)));
typedef float floatx4 __attribute__((ext_vector_type(4)));

#define GLOBAL_AS(p) ((const __attribute__((address_space(1))) void*)(p))
#define LDS_AS(p)    ((__attribute__((address_space(3))) void*)(p))

// ---------------------------------------------------------------------------
// Prep: fp32 -> fp16 casts (weights transposed to [N][K])
// ---------------------------------------------------------------------------
__global__ __launch_bounds__(256) void cast_x_kernel(
    const float* __restrict__ src, _Float16* __restrict__ dst) {
  const size_t i = ((size_t)blockIdx.x * 256 + threadIdx.x) * 8;
  float4 a = *(const float4*)(src + i);
  float4 b = *(const float4*)(src + i + 4);
  half8_t h;
  h[0] = (_Float16)a.x; h[1] = (_Float16)a.y; h[2] = (_Float16)a.z; h[3] = (_Float16)a.w;
  h[4] = (_Float16)b.x; h[5] = (_Float16)b.y; h[6] = (_Float16)b.z; h[7] = (_Float16)b.w;
  *(half8_t*)(dst + i) = h;
}

__global__ __launch_bounds__(256) void transpose_cast_kernel(
    const float* __restrict__ src, _Float16* __restrict__ dst, int R, int C) {
  __shared__ float Ls[64][65];
  const int t = threadIdx.x;
  const int r0 = blockIdx.y * 64, c0 = blockIdx.x * 64;
  {
    const int lr = t >> 2, lcg = (t & 3) * 16;
    const float* s = src + (size_t)(r0 + lr) * C + c0 + lcg;
#pragma unroll
    for (int u = 0; u < 4; ++u)
      *(float4*)&Ls[lr][lcg + 4 * u] = *(const float4*)(s + 4 * u);
  }
  __syncthreads();
  const int c = t >> 2, rg = (t & 3) * 16;
  half8_t h0, h1;
#pragma unroll
  for (int u = 0; u < 8; ++u) h0[u] = (_Float16)Ls[rg + u][c];
#pragma unroll
  for (int u = 0; u < 8; ++u) h1[u] = (_Float16)Ls[rg + 8 + u][c];
  _Float16* d = dst + (size_t)(c0 + c) * R + r0 + rg;
  *(half8_t*)d = h0;
  *(half8_t*)(d + 8) = h1;
}

// ---------------------------------------------------------------------------
// RoPE table prep + kmax init. tbl[n*32+f] = (cos, sin) of n*10000^(-f/32).
// ---------------------------------------------------------------------------
__global__ __launch_bounds__(256) void rope_prep_kernel(
    float2* __restrict__ tbl, unsigned* __restrict__ kmaxu) {
  const int idx = blockIdx.x * 256 + threadIdx.x;   // 65536 entries
  const int n = idx >> 5, f = idx & 31;
  const float invf = expf(-9.210340371976184f * ((float)f * (1.0f / 32.0f)));
  float s, c;
  sincosf((float)n * invf, &s, &c);
  tbl[idx] = make_float2(c, s);
  if (blockIdx.x == 0)
    for (int i = threadIdx.x; i < 64 * KMAX_STRIDE; i += 256) kmaxu[i] = 0u;
}

// ---------------------------------------------------------------------------
// Kernel 1: QKV GEMM (fp16 MFMA) + bias + RoPE epilogue (table-based).
// ---------------------------------------------------------------------------
__global__ __launch_bounds__(256) void qkv_gemm_kernel(
    const _Float16* __restrict__ xh, const _Float16* __restrict__ Wt,
    const float* __restrict__ bias, const float2* __restrict__ rope,
    _Float16* __restrict__ Qh, _Float16* __restrict__ Kh,
    _Float16* __restrict__ Vh) {
  __shared__ _Float16 As[128 * 64];
  __shared__ _Float16 Bs[128 * 64];
  const int tid = threadIdx.x;
  const int lane = tid & 63, w = tid >> 6;
  const int m = lane & 15, quad = lane >> 4;
  const int wr = (w >> 1) * 64, wc = (w & 1) * 64;
  const int m0 = blockIdx.y * 128;
  const int N0 = blockIdx.x * 128;
  const int sr = lane >> 3, sc = (lane & 7) * 8;

  floatx4 acc[4][4];
#pragma unroll
  for (int i = 0; i < 4; ++i)
#pragma unroll
    for (int j = 0; j < 4; ++j) acc[i][j] = (floatx4){0.f, 0.f, 0.f, 0.f};

  for (int k0 = 0; k0 < CDIM; k0 += 64) {
    __syncthreads();
#pragma unroll
    for (int i = 0; i < 4; ++i) {
      const int row = (w * 4 + i) * 8 + sr;
      __builtin_amdgcn_global_load_lds(
          GLOBAL_AS(xh + (size_t)(m0 + row) * CDIM + k0 + sc),
          LDS_AS(As + (w * 4 + i) * 512), 16, 0, 0);
      __builtin_amdgcn_global_load_lds(
          GLOBAL_AS(Wt + (size_t)(N0 + row) * CDIM + k0 + sc),
          LDS_AS(Bs + (w * 4 + i) * 512), 16, 0, 0);
    }
    __syncthreads();
#pragma unroll
    for (int ks = 0; ks < 2; ++ks) {
      half8_t af[4], bf[4];
#pragma unroll
      for (int mt = 0; mt < 4; ++mt)
        af[mt] = *(half8_t*)(As + (wr + mt * 16 + m) * 64 + ks * 32 + quad * 8);
#pragma unroll
      for (int nt = 0; nt < 4; ++nt)
        bf[nt] = *(half8_t*)(Bs + (wc + nt * 16 + m) * 64 + ks * 32 + quad * 8);
#pragma unroll
      for (int mt = 0; mt < 4; ++mt)
#pragma unroll
        for (int nt = 0; nt < 4; ++nt)
          acc[mt][nt] = __builtin_amdgcn_mfma_f32_16x16x32_f16(
              af[mt], bf[nt], acc[mt][nt], 0, 0, 0);
    }
  }

  const int F0 = N0 + wc;
  const int which = F0 >> 10;
  const int head = (F0 & 1023) >> 6;
  float bv[4];
#pragma unroll
  for (int nt = 0; nt < 4; ++nt) bv[nt] = bias[F0 + nt * 16 + m];

  if (which == 2) {
#pragma unroll
    for (int mt = 0; mt < 4; ++mt)
#pragma unroll
      for (int reg = 0; reg < 4; ++reg) {
        const int gm = m0 + wr + mt * 16 + 4 * quad + reg;
        const int b = gm >> 11, n = gm & 2047;
        const size_t vbase = ((size_t)(b * NH + head) * DH) * NSEQ + n;
#pragma unroll
        for (int nt = 0; nt < 4; ++nt)
          Vh[vbase + (size_t)(nt * 16 + m) * NSEQ] =
              (_Float16)(acc[mt][nt][reg] + bv[nt]);
      }
  } else {
    _Float16* dst = which ? Kh : Qh;
    const float qs = which ? 1.0f : 0.125f * 1.4426950408889634f;
#pragma unroll
    for (int mt = 0; mt < 4; ++mt)
#pragma unroll
      for (int reg = 0; reg < 4; ++reg) {
        const int gm = m0 + wr + mt * 16 + 4 * quad + reg;
        const int b = gm >> 11, n = gm & 2047;
        const float2 csA = rope[n * 32 + m];       // freq index m
        const float2 csB = rope[n * 32 + 16 + m];  // freq index 16+m
        const size_t obase = ((size_t)(b * NH + head) * NSEQ + n) * DH;
#pragma unroll
        for (int nt = 0; nt < 4; ++nt) {
          const float val = acc[mt][nt][reg] + bv[nt];
          const float rot = (nt < 2) ? -(acc[mt][nt + 2][reg] + bv[nt + 2])
                                     :  (acc[mt][nt - 2][reg] + bv[nt - 2]);
          const float sv = (nt & 1) ? csB.y : csA.y;
          const float cv = (nt & 1) ? csB.x : csA.x;
          dst[obase + nt * 16 + m] = (_Float16)((val * cv + rot * sv) * qs);
        }
      }
  }
}

// ---------------------------------------------------------------------------
// Norm prepass: qn[row] = ||Qh row||; kmax[bh] = max_n ||Kh row||.
// ---------------------------------------------------------------------------
__global__ __launch_bounds__(256) void qk_norms_kernel(
    const _Float16* __restrict__ Qh, const _Float16* __restrict__ Kh,
    float* __restrict__ qn, unsigned* __restrict__ kmaxu) {
  __shared__ float wmax[4];
  const int tid = threadIdx.x;
  const size_t row = (size_t)blockIdx.x * 32 + (tid >> 3);  // 32 rows, one bh
  const int c = (tid & 7) * 8;
  half8_t q8 = *(const half8_t*)(Qh + row * DH + c);
  half8_t k8 = *(const half8_t*)(Kh + row * DH + c);
  float qs = 0.f, ks = 0.f;
#pragma unroll
  for (int u = 0; u < 8; ++u) {
    const float qv = (float)q8[u], kv = (float)k8[u];
    qs += qv * qv; ks += kv * kv;
  }
  qs += __shfl_xor(qs, 1, 64); ks += __shfl_xor(ks, 1, 64);
  qs += __shfl_xor(qs, 2, 64); ks += __shfl_xor(ks, 2, 64);
  qs += __shfl_xor(qs, 4, 64); ks += __shfl_xor(ks, 4, 64);
  if ((tid & 7) == 0) qn[row] = sqrtf(qs);
  ks = fmaxf(ks, __shfl_xor(ks, 8, 64));
  ks = fmaxf(ks, __shfl_xor(ks, 16, 64));
  ks = fmaxf(ks, __shfl_xor(ks, 32, 64));
  if ((tid & 63) == 0) wmax[tid >> 6] = ks;
  __syncthreads();
  if (tid == 0) {
    const float mx = fmaxf(fmaxf(wmax[0], wmax[1]), fmaxf(wmax[2], wmax[3]));
    atomicMax(&kmaxu[(row >> 11) * KMAX_STRIDE], __float_as_uint(sqrtf(mx)));
  }
}

// ---------------------------------------------------------------------------
// Kernel 2: flash attention. R10: 512 threads / 8 waves per block, each wave
// owns 16 q-rows (halved per-wave state -> <=64 VGPR via launch_bounds(,8)
// -> 8 waves/SIMD, 32 waves/CU at 4 blocks). Single-buffer LDS staging with
// simple 2-barrier schedule: at 32 waves/CU, cross-block TLP hides staging
// latency (R6's async dbuf only mattered at 16 waves). XCD decode kept
// (FETCH 139.6 -> 24.9 MB in R9).
// ---------------------------------------------------------------------------
__global__ __launch_bounds__(512, 8) void attn_kernel(
    const _Float16* __restrict__ Qh, const _Float16* __restrict__ Kh,
    const _Float16* __restrict__ Vh, const float* __restrict__ qn,
    const unsigned* __restrict__ kmaxu, _Float16* __restrict__ AO) {
  __shared__ _Float16 smem[17408];   // 34816 B: Ks[64][72]+Vt[64][72] stage
  float* Os = (float*)smem;          // epilogue reuse: float[128][68]
  _Float16* Ks = smem;               // [64][72]
  _Float16* Vt = smem + 4608;        // [64][72]

  const int tid = threadIdx.x;
  const int lane = tid & 63;
  const int w = tid >> 6;            // 0..7
  const int m = lane & 15;
  const int quad = lane >> 4;

  // XCD-aware decode: slot = id%8 (XCD), k = id/8; bh = slot + 8*(k/16)
  const int bid = blockIdx.x;
  const int slot = bid & 7, kk = bid >> 3;
  const int bh = slot + 8 * (kk >> 4);
  const int q0 = (kk & 15) * 128;

  const _Float16* Qb = Qh + (size_t)bh * NSEQ * DH;
  const _Float16* Kb = Kh + (size_t)bh * NSEQ * DH;
  const _Float16* Vb = Vh + (size_t)bh * DH * NSEQ;

  const int rA = q0 + w * 16 + m;    // wave w owns rows q0+w*16 .. +16
  half8_t qfA0 = *(const half8_t*)(Qb + (size_t)rA * DH + quad * 8);
  half8_t qfA1 = *(const half8_t*)(Qb + (size_t)rA * DH + 32 + quad * 8);

  const float kmx = __uint_as_float(kmaxu[bh * KMAX_STRIDE]);
  const float mA = qn[(size_t)bh * NSEQ + rA] * kmx;

  // staging: 512 threads, each moves 1 K half8 + 1 V half8 per chunk
  const int skey = tid >> 3, sdg = (tid & 7) * 8;
  const _Float16* ksrc = Kb + (size_t)skey * DH + sdg;
  const _Float16* vsrc = Vb + (size_t)skey * NSEQ + sdg;
  const int koff = skey * 72 + sdg;

  float lA = 0.f;
  floatx4 OA[4];
#pragma unroll
  for (int nb = 0; nb < 4; ++nb) OA[nb] = (floatx4){0.f, 0.f, 0.f, 0.f};
  const pk2_t one2 = {(__fp16)1.f, (__fp16)1.f};

  const int NCK = NSEQ / KC;  // 32
  for (int ck = 0; ck < NCK; ++ck) {
    half8_t k8 = *(const half8_t*)ksrc;  ksrc += KC * DH;
    half8_t v8 = *(const half8_t*)vsrc;  vsrc += KC;
    __syncthreads();                 // prev compute done, LDS free
    *(half8_t*)(Ks + koff) = k8;
    *(half8_t*)(Vt + koff) = v8;
    __syncthreads();                 // stage visible

#pragma unroll
    for (int kt = 0; kt < 4; ++kt) {
      half8_t kf0 = *(half8_t*)(Ks + (kt * 16 + m) * 72 + quad * 8);
      half8_t kf1 = *(half8_t*)(Ks + (kt * 16 + m) * 72 + 32 + quad * 8);
      __builtin_amdgcn_s_setprio(1);
      floatx4 a = (floatx4){-mA, -mA, -mA, -mA};
      a = __builtin_amdgcn_mfma_f32_16x16x32_f16(kf0, qfA0, a, 0, 0, 0);
      a = __builtin_amdgcn_mfma_f32_16x16x32_f16(kf1, qfA1, a, 0, 0, 0);
      __builtin_amdgcn_s_setprio(0);

      pk2_t a01 = __builtin_amdgcn_cvt_pkrtz(__builtin_exp2f(a[0]),
                                             __builtin_exp2f(a[1]));
      pk2_t a23 = __builtin_amdgcn_cvt_pkrtz(__builtin_exp2f(a[2]),
                                             __builtin_exp2f(a[3]));
      lA = __builtin_amdgcn_fdot2(a01, one2, lA, false);
      lA = __builtin_amdgcn_fdot2(a23, one2, lA, false);
      half4_t phA = __builtin_bit_cast(
          half4_t, (pk4_t)__builtin_shufflevector(a01, a23, 0, 1, 2, 3));

      __builtin_amdgcn_s_setprio(1);
#pragma unroll
      for (int nb = 0; nb < 4; ++nb) {
        half4_t vf = *(half4_t*)(Vt + (nb * 16 + m) * 72 + kt * 16 + quad * 4);
        OA[nb] = __builtin_amdgcn_mfma_f32_16x16x16f16(phA, vf, OA[nb], 0, 0, 0);
      }
      __builtin_amdgcn_s_setprio(0);
    }
  }

  // row-sum across quads (lanes differing in bits 4,5)
  lA += __shfl_xor(lA, 16, 64); lA += __shfl_xor(lA, 32, 64);
  float lA4[4];
#pragma unroll
  for (int r = 0; r < 4; ++r) lA4[r] = __shfl(lA, 4 * quad + r, 64);

  const int b = bh >> 4, h = bh & 15;
  const int ql = tid >> 2, dgo = (tid & 3) * 16;   // ql 0..127
  const int gq = q0 + ql;
  _Float16* dst = AO + ((size_t)(b * NSEQ + gq)) * CDIM + h * DH + dgo;

  __syncthreads();   // all compute reads of Ks/Vt done before Os overwrite
#pragma unroll
  for (int nb = 0; nb < 4; ++nb)
#pragma unroll
    for (int r = 0; r < 4; ++r)
      Os[(w * 16 + 4 * quad + r) * 68 + nb * 16 + m] = OA[nb][r] * (1.0f / lA4[r]);
  __syncthreads();
#pragma unroll
  for (int u = 0; u < 2; ++u) {
    half8_t o;
#pragma unroll
    for (int v = 0; v < 8; ++v) o[v] = (_Float16)Os[ql * 68 + dgo + u * 8 + v];
    *(half8_t*)(dst + u * 8) = o;
  }
}

// ---------------------------------------------------------------------------
// Kernel 3: proj GEMM (fp16 MFMA) + bias, fp32 out (unchanged R3).
// ---------------------------------------------------------------------------
__global__ __launch_bounds__(256) void proj_gemm_kernel(
    const _Float16* __restrict__ Ah, const _Float16* __restrict__ Wt,
    const float* __restrict__ bias, float* __restrict__ out) {
  __shared__ _Float16 As[128 * 64];
  __shared__ _Float16 Bs[128 * 64];
  const int tid = threadIdx.x;
  const int lane = tid & 63, w = tid >> 6;
  const int m = lane & 15, quad = lane >> 4;
  const int wr = (w >> 1) * 64, wc = (w & 1) * 64;
  const int m0 = blockIdx.y * 128;
  const int N0 = blockIdx.x * 128;
  const int sr = lane >> 3, sc = (lane & 7) * 8;

  floatx4 acc[4][4];
#pragma unroll
  for (int i = 0; i < 4; ++i)
#pragma unroll
    for (int j = 0; j < 4; ++j) acc[i][j] = (floatx4){0.f, 0.f, 0.f, 0.f};

  for (int k0 = 0; k0 < CDIM; k0 += 64) {
    __syncthreads();
#pragma unroll
    for (int i = 0; i < 4; ++i) {
      const int row = (w * 4 + i) * 8 + sr;
      __builtin_amdgcn_global_load_lds(
          GLOBAL_AS(Ah + (size_t)(m0 + row) * CDIM + k0 + sc),
          LDS_AS(As + (w * 4 + i) * 512), 16, 0, 0);
      __builtin_amdgcn_global_load_lds(
          GLOBAL_AS(Wt + (size_t)(N0 + row) * CDIM + k0 + sc),
          LDS_AS(Bs + (w * 4 + i) * 512), 16, 0, 0);
    }
    __syncthreads();
#pragma unroll
    for (int ks = 0; ks < 2; ++ks) {
      half8_t af[4], bf[4];
#pragma unroll
      for (int mt = 0; mt < 4; ++mt)
        af[mt] = *(half8_t*)(As + (wr + mt * 16 + m) * 64 + ks * 32 + quad * 8);
#pragma unroll
      for (int nt = 0; nt < 4; ++nt)
        bf[nt] = *(half8_t*)(Bs + (wc + nt * 16 + m) * 64 + ks * 32 + quad * 8);
#pragma unroll
      for (int mt = 0; mt < 4; ++mt)
#pragma unroll
        for (int nt = 0; nt < 4; ++nt)
          acc[mt][nt] = __builtin_amdgcn_mfma_f32_16x16x32_f16(
              af[mt], bf[nt], acc[mt][nt], 0, 0, 0);
    }
  }

  const int F0 = N0 + wc;
  float bv[4];
#pragma unroll
  for (int nt = 0; nt < 4; ++nt) bv[nt] = bias[F0 + nt * 16 + m];
#pragma unroll
  for (int mt = 0; mt < 4; ++mt)
#pragma unroll
    for (int reg = 0; reg < 4; ++reg) {
      const int gm = m0 + wr + mt * 16 + 4 * quad + reg;
#pragma unroll
      for (int nt = 0; nt < 4; ++nt)
        out[(size_t)gm * CDIM + F0 + nt * 16 + m] = acc[mt][nt][reg] + bv[nt];
    }
}

// ---------------------------------------------------------------------------
extern "C" void kernel_launch(void* const* d_in, const int* in_sizes, int n_in,
                              void* d_out, int out_size, void* d_ws, size_t ws_size,
                              hipStream_t stream) {
  const float* x     = (const float*)d_in[0];
  const float* Wqkv  = (const float*)d_in[1];
  const float* bqkv  = (const float*)d_in[2];
  const float* Wproj = (const float*)d_in[3];
  const float* bproj = (const float*)d_in[4];
  float* out = (float*)d_out;

  const size_t per = (size_t)BSZ * NH * NSEQ * DH;  // 8,388,608
  _Float16* xh  = (_Float16*)d_ws;
  _Float16* Wt  = xh + per;                 // [3072][1024]
  _Float16* Wpt = Wt + (size_t)3072 * 1024; // [1024][1024]
  _Float16* Qh  = Wpt + (size_t)1024 * 1024;
  _Float16* Kh  = Qh + per;
  _Float16* Vh  = Kh + per;
  _Float16* AOh = Vh + per;
  float*    qnp = (float*)(AOh + per);      // [64*2048] q-row norms
  unsigned* kmx = (unsigned*)(qnp + (size_t)64 * NSEQ);  // [64*KMAX_STRIDE]
  float2*   ropet = (float2*)(kmx + 64 * KMAX_STRIDE);   // [2048*32] (cos,sin)

  cast_x_kernel<<<4096, 256, 0, stream>>>(x, xh);
  transpose_cast_kernel<<<dim3(48, 16), 256, 0, stream>>>(Wqkv, Wt, 1024, 3072);
  transpose_cast_kernel<<<dim3(16, 16), 256, 0, stream>>>(Wproj, Wpt, 1024, 1024);
  rope_prep_kernel<<<256, 256, 0, stream>>>(ropet, kmx);
  qkv_gemm_kernel<<<dim3(24, 64), 256, 0, stream>>>(xh, Wt, bqkv, ropet, Qh, Kh, Vh);
  qk_norms_kernel<<<4096, 256, 0, stream>>>(Qh, Kh, qnp, kmx);
  attn_kernel<<<1024, 512, 0, stream>>>(Qh, Kh, Vh, qnp, kmx, AOh);
  proj_gemm_kernel<<<dim3(8, 64), 256, 0, stream>>>(AOh, Wpt, bproj, out);
}